// Round 16
// baseline (706.989 us; speedup 1.0000x reference)
//
#include <hip/hip_runtime.h>
#include <hip/hip_bf16.h>
#include <math.h>

namespace {

constexpr int Dm  = 2048;
constexpr int FFm = 8192;
constexpr int SEQ = 2048;
constexpr int HDm = 128;
constexpr int MR  = 4096;     // B*S
constexpr int QW  = 3 * Dm;   // 6144

typedef __bf16 bf16_t;
typedef __bf16 bf16x8 __attribute__((ext_vector_type(8)));
typedef float  f32x4  __attribute__((ext_vector_type(4)));

typedef __attribute__((address_space(1))) const void as1_void;
typedef __attribute__((address_space(3))) void as3_void;

__device__ __forceinline__ void gload_lds16(const void* g, void* l) {
  __builtin_amdgcn_global_load_lds((as1_void*)g, (as3_void*)l, 16, 0, 0);
}

// ---------------- LayerNorm: fp32 in -> bf16 out ----------------
__global__ __launch_bounds__(256)
void ln_kernel(const float* __restrict__ x, const float* __restrict__ sc,
               const float* __restrict__ sh, bf16_t* __restrict__ out)
{
  const int row = blockIdx.x;
  const int tid = threadIdx.x;
  const float4* xr = (const float4*)(x + (size_t)row * Dm);
  float4 v0 = xr[tid*2], v1 = xr[tid*2+1];
  float s  = v0.x+v0.y+v0.z+v0.w + v1.x+v1.y+v1.z+v1.w;
  float s2 = v0.x*v0.x+v0.y*v0.y+v0.z*v0.z+v0.w*v0.w
           + v1.x*v1.x+v1.y*v1.y+v1.z*v1.z+v1.w*v1.w;
  #pragma unroll
  for (int off = 32; off; off >>= 1) { s += __shfl_xor(s, off); s2 += __shfl_xor(s2, off); }
  __shared__ float red[8];
  if ((tid & 63) == 0) { red[(tid>>6)*2] = s; red[(tid>>6)*2+1] = s2; }
  __syncthreads();
  s  = red[0]+red[2]+red[4]+red[6];
  s2 = red[1]+red[3]+red[5]+red[7];
  const float mean = s * (1.f/Dm);
  const float var  = fmaxf(s2 * (1.f/Dm) - mean*mean, 0.f);
  const float rstd = rsqrtf(var + 1e-5f);
  const float4* scp = (const float4*)sc;
  const float4* shp = (const float4*)sh;
  float4 sc0 = scp[tid*2], sc1 = scp[tid*2+1];
  float4 sh0 = shp[tid*2], sh1 = shp[tid*2+1];
  __attribute__((aligned(16))) bf16_t ob[8];
  ob[0] = (bf16_t)((v0.x-mean)*rstd*sc0.x + sh0.x);
  ob[1] = (bf16_t)((v0.y-mean)*rstd*sc0.y + sh0.y);
  ob[2] = (bf16_t)((v0.z-mean)*rstd*sc0.z + sh0.z);
  ob[3] = (bf16_t)((v0.w-mean)*rstd*sc0.w + sh0.w);
  ob[4] = (bf16_t)((v1.x-mean)*rstd*sc1.x + sh1.x);
  ob[5] = (bf16_t)((v1.y-mean)*rstd*sc1.y + sh1.y);
  ob[6] = (bf16_t)((v1.z-mean)*rstd*sc1.z + sh1.z);
  ob[7] = (bf16_t)((v1.w-mean)*rstd*sc1.w + sh1.w);
  *(uint4*)(out + (size_t)row*Dm + tid*8) = *(const uint4*)ob;
}

// -- fused: v = p0+p1+bias+resid; x1 = v (f32); out = LN(v) (bf16) --
__global__ __launch_bounds__(256)
void ln_fused(const float* __restrict__ p0, const float* __restrict__ p1,
              const float* __restrict__ bias, const float* __restrict__ resid,
              const float* __restrict__ sc, const float* __restrict__ sh,
              float* __restrict__ x1, bf16_t* __restrict__ out)
{
  const int row = blockIdx.x;
  const int tid = threadIdx.x;
  const size_t base = (size_t)row * Dm + tid*8;
  float v[8];
  #pragma unroll
  for (int hh = 0; hh < 2; ++hh) {
    float4 a  = *(const float4*)(p0 + base + hh*4);
    float4 b  = *(const float4*)(p1 + base + hh*4);
    float4 r  = *(const float4*)(resid + base + hh*4);
    float4 bv = *(const float4*)(bias + tid*8 + hh*4);
    v[hh*4+0] = a.x + b.x + bv.x + r.x;
    v[hh*4+1] = a.y + b.y + bv.y + r.y;
    v[hh*4+2] = a.z + b.z + bv.z + r.z;
    v[hh*4+3] = a.w + b.w + bv.w + r.w;
  }
  *(float4*)(x1 + base)     = *(const float4*)&v[0];
  *(float4*)(x1 + base + 4) = *(const float4*)&v[4];
  float s = 0.f, s2 = 0.f;
  #pragma unroll
  for (int j = 0; j < 8; ++j) { s += v[j]; s2 += v[j]*v[j]; }
  #pragma unroll
  for (int off = 32; off; off >>= 1) { s += __shfl_xor(s, off); s2 += __shfl_xor(s2, off); }
  __shared__ float red[8];
  if ((tid & 63) == 0) { red[(tid>>6)*2] = s; red[(tid>>6)*2+1] = s2; }
  __syncthreads();
  s  = red[0]+red[2]+red[4]+red[6];
  s2 = red[1]+red[3]+red[5]+red[7];
  const float mean = s * (1.f/Dm);
  const float var  = fmaxf(s2 * (1.f/Dm) - mean*mean, 0.f);
  const float rstd = rsqrtf(var + 1e-5f);
  __attribute__((aligned(16))) bf16_t ob[8];
  #pragma unroll
  for (int hh = 0; hh < 2; ++hh) {
    float4 scv = *(const float4*)(sc + tid*8 + hh*4);
    float4 shv = *(const float4*)(sh + tid*8 + hh*4);
    ob[hh*4+0] = (bf16_t)((v[hh*4+0]-mean)*rstd*scv.x + shv.x);
    ob[hh*4+1] = (bf16_t)((v[hh*4+1]-mean)*rstd*scv.y + shv.y);
    ob[hh*4+2] = (bf16_t)((v[hh*4+2]-mean)*rstd*scv.z + shv.z);
    ob[hh*4+3] = (bf16_t)((v[hh*4+3]-mean)*rstd*scv.w + shv.w);
  }
  *(uint4*)(out + base) = *(const uint4*)ob;
}

// ----- weights q,k,v,o (each [Dm][Dm] fp32) -> bf16 transposed, packed -----
__global__ __launch_bounds__(256)
void wconv4(const float* __restrict__ wq, const float* __restrict__ wk,
            const float* __restrict__ wv, const float* __restrict__ wo,
            bf16_t* __restrict__ dst)
{
  const int z = blockIdx.z;
  const float* W = (z == 0) ? wq : (z == 1) ? wk : (z == 2) ? wv : wo;
  bf16_t* WT = dst + (size_t)z * Dm * Dm;
  __shared__ float tile[32][33];
  const int tx = threadIdx.x & 31, ty = threadIdx.x >> 5;
  const int nb = blockIdx.x * 32, kb = blockIdx.y * 32;
  #pragma unroll
  for (int p = 0; p < 4; ++p)
    tile[ty+8*p][tx] = W[(size_t)(kb+ty+8*p)*Dm + nb + tx];
  __syncthreads();
  #pragma unroll
  for (int p = 0; p < 4; ++p)
    WT[(size_t)(nb+ty+8*p)*Dm + kb + tx] = (bf16_t)tile[tx][ty+8*p];
}

// ------------- weight fp32 [K][N] -> bf16 transposed [N][K] -------------
__global__ __launch_bounds__(256)
void wconv_t(const float* __restrict__ W, bf16_t* __restrict__ WT, int K, int N)
{
  __shared__ float tile[32][33];
  const int tx = threadIdx.x & 31, ty = threadIdx.x >> 5;
  const int nb = blockIdx.x * 32, kb = blockIdx.y * 32;
  #pragma unroll
  for (int p = 0; p < 4; ++p)
    tile[ty+8*p][tx] = W[(size_t)(kb+ty+8*p)*N + nb + tx];
  __syncthreads();
  #pragma unroll
  for (int p = 0; p < 4; ++p)
    WT[(size_t)(nb+ty+8*p)*K + kb + tx] = (bf16_t)tile[tx][ty+8*p];
}

__global__ void bias_concat(const float* __restrict__ bq, const float* __restrict__ bk,
                            const float* __restrict__ bv, float* __restrict__ o)
{
  int i = blockIdx.x*256 + threadIdx.x;
  o[i] = bq[i]; o[Dm+i] = bk[i]; o[2*Dm+i] = bv[i];
}

// ----- V slice of qkv [B*S][6144] -> vT [B*H][128][2048] (bf16) -----
__global__ __launch_bounds__(256)
void vtrans(const bf16_t* __restrict__ qkv, bf16_t* __restrict__ vT)
{
  __shared__ bf16_t tile[32][33];
  const int tx = threadIdx.x & 31, ty = threadIdx.x >> 5;
  const int s0 = blockIdx.x*32, d0 = blockIdx.y*32, bh = blockIdx.z;
  const int b = bh >> 4, h = bh & 15;
  const bf16_t* src = qkv + (size_t)(b*SEQ)*QW + 2*Dm + h*HDm;
  #pragma unroll
  for (int p = 0; p < 4; ++p)
    tile[ty+8*p][tx] = src[(size_t)(s0+ty+8*p)*QW + d0 + tx];
  __syncthreads();
  bf16_t* dst = vT + (size_t)bh*HDm*SEQ;
  #pragma unroll
  for (int p = 0; p < 4; ++p)
    dst[(size_t)(d0+ty+8*p)*SEQ + s0 + tx] = tile[tx][ty+8*p];
}

// ---- GEMM 256x256, 8-phase, 2 K-tiles(BK=64)/iter, 8 waves (2Mx4N) ----
// MODE: 0 bf16+bias | 1 bf16+bias+GELU | 3 f32 raw partial (split-K)
template<int MODE>
__global__ __launch_bounds__(512, 2)
void gemm8p(const bf16_t* __restrict__ A, const bf16_t* __restrict__ BT,
            const float* __restrict__ bias,
            void* __restrict__ Cout, void* __restrict__ Cout2,
            int Ndim, int Kslice, int Kstride, int gn)
{
  // 2D XCD chunking: 2x4 chunk grid; chunk = bid&7 (XCD-pinned)
  const int gm = (int)gridDim.x / gn;
  const int cm = gm >> 1, cn = gn >> 2;
  const int c = blockIdx.x & 7;
  const int idx = blockIdx.x >> 3;
  const int mi = idx / cn, ni = idx - mi*cn;
  const int m0 = ((c >> 2)*cm + mi) * 256;
  const int n0 = ((c & 3)*cn + ni) * 256;
  const int kOff = blockIdx.y * Kslice;
  const int tid = threadIdx.x;
  const int lane = tid & 63;
  const int w = tid >> 6;
  const int wr = w >> 2, wc = w & 3;              // 2 x 4 waves
  const int lr = lane & 15, kg = lane >> 4;

  // 8 regions of 8192 elems: buf0{r0:A-h0, r1:A-h1, r2:B-h0, r3:B-h1} buf1{r4..r7}
  __shared__ __attribute__((aligned(16))) bf16_t lds[65536];

  f32x4 acc[8][4] = {};

  // --- staging: 4 streams, incremental pointers (+64 elems per call) ---
  const int r1   = tid >> 3;
  const int blk1 = (tid & 7) ^ (r1 & 7);
  const size_t rowoff = (size_t)64 * Kstride;
  const bf16_t* pA0 = A  + (size_t)(m0 + r1)*Kstride       + kOff + blk1*8;
  const bf16_t* pA1 = A  + (size_t)(m0 + 128 + r1)*Kstride + kOff + blk1*8;
  const bf16_t* pB0 = BT + (size_t)(n0 + r1)*Kstride       + kOff + blk1*8;
  const bf16_t* pB1 = BT + (size_t)(n0 + 128 + r1)*Kstride + kOff + blk1*8;
  bf16_t* const d0 = lds + (size_t)tid*8;

#define STG(p, region) do { \
    gload_lds16((p), d0 + (size_t)(region)*8192); \
    gload_lds16((p) + rowoff, d0 + (size_t)(region)*8192 + 4096); \
    (p) += 64; } while (0)

  // read A-half mh: rows wr*64 + ml*16 + lr within region (buf*4 + mh)
  auto readA = [&](int buf, int mh, bf16x8* f) {
    #pragma unroll
    for (int ml = 0; ml < 4; ++ml)
      #pragma unroll
      for (int kk = 0; kk < 2; ++kk) {
        const bf16_t* base = lds + (buf*4 + mh)*8192;
        const int row = wr*64 + ml*16 + lr;
        f[ml*2+kk] = *(const bf16x8*)(base + row*64 + (((kk*4+kg) ^ (row&7))*8));
      }
  };
  // read B-half nh: rows wc*32 + nl*16 + lr within region (buf*4 + 2 + nh)
  auto readB = [&](int buf, int nh, bf16x8* f) {
    #pragma unroll
    for (int nl = 0; nl < 2; ++nl)
      #pragma unroll
      for (int kk = 0; kk < 2; ++kk) {
        const bf16_t* base = lds + (buf*4 + 2 + nh)*8192;
        const int row = wc*32 + nl*16 + lr;
        f[nl*2+kk] = *(const bf16x8*)(base + row*64 + (((kk*4+kg) ^ (row&7))*8));
      }
  };
  auto mfma16 = [&](int mh, int nh, const bf16x8* Af, const bf16x8* Bf) {
    __builtin_amdgcn_s_setprio(1);
    #pragma unroll
    for (int ml = 0; ml < 4; ++ml)
      #pragma unroll
      for (int nl = 0; nl < 2; ++nl)
        #pragma unroll
        for (int kk = 0; kk < 2; ++kk)
          acc[mh*4+ml][nh*2+nl] =
            __builtin_amdgcn_mfma_f32_16x16x32_bf16(Af[ml*2+kk], Bf[nl*2+kk],
                                                    acc[mh*4+ml][nh*2+nl], 0, 0, 0);
    __builtin_amdgcn_s_setprio(0);
  };

#define BAR() __builtin_amdgcn_s_barrier()
#define LGKM0() asm volatile("s_waitcnt lgkmcnt(0)")

  bf16x8 Af0[8], Af1[8], Bf0[4], Bf1[4];      // even K-tile set
  bf16x8 Af0b[8], Af1b[8], Bf0b[4], Bf1b[4];  // odd K-tile set

  // prologue: stage t0 (r0-r3) then t1 (r4-r7); vmcnt(8) -> t0 resident.
  STG(pA0, 0); STG(pA1, 1); STG(pB0, 2); STG(pB1, 3);
  STG(pA0, 4); STG(pA1, 5); STG(pB0, 6); STG(pB1, 7);
  asm volatile("s_waitcnt vmcnt(8)" ::: "memory");
  BAR();

  const int NITER = Kslice >> 7;     // iterations of 2 K-tiles
  for (int j = 0; j < NITER; ++j) {
    const bool s2 = (j + 1 < NITER);

    // P1: reads r0 (A-h0 t0) + r2 (B-h0 t0); no stage
    readA(0, 0, Af0); readB(0, 0, Bf0);
    BAR(); LGKM0(); mfma16(0, 0, Af0, Bf0); BAR();

    // P2: reads r3 (B-h1 t0); stage r0 <- A-h0(t0+2)   [r0 last read P1]
    readB(0, 1, Bf1);
    if (s2) STG(pA0, 0);
    BAR(); LGKM0(); mfma16(0, 1, Af0, Bf1); BAR();

    // P3: reads r1 (A-h1 t0); stage r2 <- B-h0(t0+2)   [r2 last read P1]
    readA(0, 1, Af1);
    if (s2) STG(pB0, 2);
    BAR(); LGKM0(); mfma16(1, 1, Af1, Bf1);
    if (s2) asm volatile("s_waitcnt vmcnt(4)" ::: "memory");
    else    asm volatile("s_waitcnt vmcnt(0)" ::: "memory");
    BAR();

    // P4: reads r4 (A-h0 t1); stage r1 <- A-h1(t0+2), r3 <- B-h1(t0+2)
    readA(1, 0, Af0b);
    if (s2) { STG(pA1, 1); STG(pB1, 3); }
    BAR(); LGKM0(); mfma16(1, 0, Af1, Bf0); BAR();

    // P5: reads r6 (B-h0 t1); no stage
    readB(1, 0, Bf0b);
    BAR(); LGKM0(); mfma16(0, 0, Af0b, Bf0b); BAR();

    // P6: reads r7 (B-h1 t1); stage r4 <- A-h0(t1+2), r6 <- B-h0(t1+2)
    readB(1, 1, Bf1b);
    if (s2) { STG(pA0, 4); STG(pB0, 6); }
    BAR(); LGKM0(); mfma16(0, 1, Af0b, Bf1b); BAR();

    // P7: reads r5 (A-h1 t1); stage r7 <- B-h1(t1+2)   [r7 last read P6]
    readA(1, 1, Af1b);
    if (s2) STG(pB1, 7);
    BAR(); LGKM0(); mfma16(1, 1, Af1b, Bf1b); BAR();

    // P8: stage r5 <- A-h1(t1+2)                       [r5 last read P7]
    if (s2) STG(pA1, 5);
    BAR(); mfma16(1, 0, Af1b, Bf0b);
    if (s2) asm volatile("s_waitcnt vmcnt(8)" ::: "memory");
    else    asm volatile("s_waitcnt vmcnt(0)" ::: "memory");
    BAR();
  }
#undef STG
#undef BAR
#undef LGKM0

  // ---- epilogue ----
  // row(MF) = (MF>>2)*128 + wr*64 + (MF&3)*16 + kg*4 + jj
  // col(NF) = (NF>>1)*128 + wc*32 + (NF&1)*16 + lr
  if constexpr (MODE == 0 || MODE == 1) {
    __syncthreads();
    #pragma unroll
    for (int NF = 0; NF < 4; ++NF) {
      const int col = (NF>>1)*128 + wc*32 + (NF&1)*16 + lr;
      const float bv = bias[n0 + col];
      #pragma unroll
      for (int MF = 0; MF < 8; ++MF) {
        #pragma unroll
        for (int jj = 0; jj < 4; ++jj) {
          float v = acc[MF][NF][jj] + bv;
          if constexpr (MODE == 1) v = 0.5f*v*(1.f + erff(v*0.70710678118f));
          const int row = (MF>>2)*128 + wr*64 + (MF&3)*16 + kg*4 + jj;
          const int adr = row*256 + (((col >> 3) ^ (row & 7)) << 3) + (col & 7);
          lds[adr] = (bf16_t)v;
        }
      }
    }
    __syncthreads();
    bf16_t* outp = (bf16_t*)Cout;
    #pragma unroll
    for (int i = 0; i < 16; ++i) {
      const int s = tid + i*512;
      const int row = s >> 5, ch = s & 31;
      uint4 vv = *(const uint4*)(lds + row*256 + ((ch ^ (row & 7)) << 3));
      *(uint4*)(outp + (size_t)(m0 + row)*Ndim + n0 + ch*8) = vv;
    }
  } else {
    float* pout = (float*)(blockIdx.y ? Cout2 : Cout);
    #pragma unroll
    for (int NF = 0; NF < 4; ++NF) {
      const int col = n0 + (NF>>1)*128 + wc*32 + (NF&1)*16 + lr;
      #pragma unroll
      for (int MF = 0; MF < 8; ++MF) {
        const int rbase = m0 + (MF>>2)*128 + wr*64 + (MF&3)*16 + kg*4;
        #pragma unroll
        for (int jj = 0; jj < 4; ++jj)
          pout[(size_t)(rbase + jj)*Ndim + col] = acc[MF][NF][jj];
      }
    }
  }
}

// ---- split-K reduce: out = p0 + p1 + bias + resid (f32, Ndim pow2) ----
__global__ __launch_bounds__(256)
void splitk_reduce(const float* __restrict__ p0, const float* __restrict__ p1,
                   const float* __restrict__ bias, const float* __restrict__ resid,
                   float* __restrict__ out, int Ndim)
{
  const size_t e = ((size_t)blockIdx.x*256 + threadIdx.x) * 4;
  float4 a = *(const float4*)(p0 + e);
  float4 b = *(const float4*)(p1 + e);
  float4 r = *(const float4*)(resid + e);
  float4 bv = *(const float4*)(bias + (int)(e & (size_t)(Ndim - 1)));
  float4 o;
  o.x = a.x + b.x + bv.x + r.x;
  o.y = a.y + b.y + bv.y + r.y;
  o.z = a.z + b.z + bv.z + r.z;
  o.w = a.w + b.w + bv.w + r.w;
  *(float4*)(out + e) = o;
}

// ------- causal flash attention v6: 512 blocks x 4 waves, 2-3 blk/CU -------
// One 128-row q-tile per block; longest-first dispatch; XCD-pinned heads.
__global__ __launch_bounds__(256)
void flash_attn6(const bf16_t* __restrict__ qkv, const bf16_t* __restrict__ vT,
                 bf16_t* __restrict__ ctx)
{
  const int bid = blockIdx.x;                  // 0..511
  const int bh  = (bid & 7) + 8 * ((bid >> 3) & 3);  // XCD-pinned head
  const int qi  = 15 - (bid >> 5);             // longest q-tiles first
  const int b = bh >> 4, h = bh & 15;
  const int Q0 = qi * 128;
  const int tid = threadIdx.x;
  const int lane = tid & 63;
  const int w = tid >> 6;                      // 0..3
  const int lr = lane & 15, kg = lane >> 4;
  const int q0w = Q0 + w * 32;

  __shared__ __attribute__((aligned(16))) bf16_t Ks[64*128];
  __shared__ __attribute__((aligned(16))) bf16_t Vs[128*64];
  __shared__ __attribute__((aligned(16))) bf16_t Plds[4*2048];

  const bf16_t* kbase = qkv + (size_t)(b*SEQ)*QW + Dm + h*HDm;
  const bf16_t* vbase = vT + (size_t)bh*HDm*SEQ;
  const float scl = 0.08838834764831845f * 1.44269504089f; // 1/sqrt(128)*log2(e)

  auto stage = [&](int k0) {
    #pragma unroll
    for (int i = 0; i < 4; ++i) {
      const int s = tid + i*256;                 // K slot (1024 total)
      const int row = s >> 4, sl = s & 15;
      gload_lds16(kbase + (size_t)(k0 + row)*QW + (sl ^ (row & 7))*8, Ks + s*8);
    }
    #pragma unroll
    for (int i = 0; i < 4; ++i) {
      const int s = tid + i*256;                 // V slot (1024 total)
      const int row = s >> 3, sl = s & 7;
      gload_lds16(vbase + (size_t)row*SEQ + k0 + (sl ^ (row & 7))*8, Vs + s*8);
    }
  };

  bf16x8 qf[2][4];
  #pragma unroll
  for (int rt = 0; rt < 2; ++rt) {
    const bf16_t* qb = qkv + (size_t)(b*SEQ + q0w + rt*16 + lr)*QW + h*HDm;
    #pragma unroll
    for (int g = 0; g < 4; ++g)
      qf[rt][g] = *(const bf16x8*)(qb + g*32 + kg*8);
  }

  float mrow[2][4], lsum[2][4];
  f32x4 oacc[2][8];
  #pragma unroll
  for (int rt = 0; rt < 2; ++rt) {
    #pragma unroll
    for (int j = 0; j < 4; ++j) { mrow[rt][j] = -INFINITY; lsum[rt][j] = 0.f; }
    #pragma unroll
    for (int dt = 0; dt < 8; ++dt) oacc[rt][dt] = (f32x4){0.f,0.f,0.f,0.f};
  }

  const int nsteps = (Q0 + 128) >> 6;
  stage(0);
  for (int t = 0; t < nsteps; ++t) {
    const int k0 = t * 64;
    __syncthreads();                             // staging complete
    if (k0 < q0w + 32) {
      f32x4 sa[2][4];
      #pragma unroll
      for (int rt = 0; rt < 2; ++rt)
        #pragma unroll
        for (int ct = 0; ct < 4; ++ct) sa[rt][ct] = (f32x4){0.f,0.f,0.f,0.f};
      #pragma unroll
      for (int ct = 0; ct < 4; ++ct) {
        const int krow = ct*16 + lr;
        #pragma unroll
        for (int g = 0; g < 4; ++g) {
          bf16x8 kf = *(const bf16x8*)(Ks + krow*128 + ((4*g + kg) ^ (krow & 7))*8);
          sa[0][ct] = __builtin_amdgcn_mfma_f32_16x16x32_bf16(qf[0][g], kf, sa[0][ct], 0, 0, 0);
          sa[1][ct] = __builtin_amdgcn_mfma_f32_16x16x32_bf16(qf[1][g], kf, sa[1][ct], 0, 0, 0);
        }
      }
      #pragma unroll
      for (int rt = 0; rt < 2; ++rt)
        #pragma unroll
        for (int ct = 0; ct < 4; ++ct)
          #pragma unroll
          for (int j = 0; j < 4; ++j) sa[rt][ct][j] *= scl;
      if (k0 + 63 > q0w) {
        #pragma unroll
        for (int ct = 0; ct < 4; ++ct) {
          const int kidx = k0 + ct*16 + lr;
          #pragma unroll
          for (int rt = 0; rt < 2; ++rt)
            #pragma unroll
            for (int j = 0; j < 4; ++j) {
              const int qidx = q0w + rt*16 + kg*4 + j;
              if (kidx > qidx) sa[rt][ct][j] = -INFINITY;
            }
        }
      }
      #pragma unroll
      for (int rt = 0; rt < 2; ++rt) {
        #pragma unroll
        for (int j = 0; j < 4; ++j) {
          const int prow = kg*4 + j;
          float x0 = sa[rt][0][j], x1 = sa[rt][1][j], x2 = sa[rt][2][j], x3 = sa[rt][3][j];
          float v = fmaxf(fmaxf(x0, x1), fmaxf(x2, x3));
          v = fmaxf(v, __shfl_xor(v, 1));
          v = fmaxf(v, __shfl_xor(v, 2));
          v = fmaxf(v, __shfl_xor(v, 4));
          v = fmaxf(v, __shfl_xor(v, 8));
          const float mn = fmaxf(mrow[rt][j], v);
          const float alpha = exp2f(mrow[rt][j] - mn);
          mrow[rt][j] = mn;
          float p0 = exp2f(x0 - mn), p1 = exp2f(x1 - mn);
          float p2 = exp2f(x2 - mn), p3 = exp2f(x3 - mn);
          float ss = (p0 + p1) + (p2 + p3);
          ss += __shfl_xor(ss, 1);
          ss += __shfl_xor(ss, 2);
          ss += __shfl_xor(ss, 4);
          ss += __shfl_xor(ss, 8);
          lsum[rt][j] = lsum[rt][j]*alpha + ss;
          #pragma unroll
          for (int dt = 0; dt < 8; ++dt) oacc[rt][dt][j] *= alpha;
          const int base = w*2048 + rt*1024 + prow*64;
          const int sw = (prow & 7) << 3;
          Plds[(base + ( 0 + lr)) ^ sw] = (bf16_t)p0;
          Plds[(base + (16 + lr)) ^ sw] = (bf16_t)p1;
          Plds[(base + (32 + lr)) ^ sw] = (bf16_t)p2;
          Plds[(base + (48 + lr)) ^ sw] = (bf16_t)p3;
        }
      }
      bf16x8 pf[2][2];
      {
        const int sw = (lr & 7) << 3;
        #pragma unroll
        for (int rt = 0; rt < 2; ++rt) {
          pf[rt][0] = *(const bf16x8*)(Plds + ((w*2048 + rt*1024 + lr*64 +      kg*8) ^ sw));
          pf[rt][1] = *(const bf16x8*)(Plds + ((w*2048 + rt*1024 + lr*64 + 32 + kg*8) ^ sw));
        }
      }
      #pragma unroll
      for (int dt = 0; dt < 8; ++dt) {
        const int vrow = dt*16 + lr;
        #pragma unroll
        for (int kc = 0; kc < 2; ++kc) {
          bf16x8 vf = *(const bf16x8*)(Vs + vrow*64 + ((4*kc + kg) ^ (vrow & 7))*8);
          oacc[0][dt] = __builtin_amdgcn_mfma_f32_16x16x32_bf16(pf[0][kc], vf, oacc[0][dt], 0, 0, 0);
          oacc[1][dt] = __builtin_amdgcn_mfma_f32_16x16x32_bf16(pf[1][kc], vf, oacc[1][dt], 0, 0, 0);
        }
      }
    }
    __syncthreads();                             // all reads of Ks/Vs done
    if (t + 1 < nsteps) stage((t + 1) * 64);
  }

  #pragma unroll
  for (int rt = 0; rt < 2; ++rt) {
    bf16_t* cb = ctx + (size_t)(b*SEQ + q0w + rt*16 + kg*4)*Dm + h*HDm;
    #pragma unroll
    for (int j = 0; j < 4; ++j) {
      const float inv = 1.f / lsum[rt][j];
      #pragma unroll
      for (int dt = 0; dt < 8; ++dt)
        cb[(size_t)j*Dm + dt*16 + lr] = (bf16_t)(oacc[rt][dt][j] * inv);
    }
  }
}

} // namespace

extern "C" void kernel_launch(void* const* d_in, const int* in_sizes, int n_in,
                              void* d_out, int out_size, void* d_ws, size_t ws_size,
                              hipStream_t stream)
{
  const float* x   = (const float*)d_in[0];
  const float* g1  = (const float*)d_in[1];
  const float* s1  = (const float*)d_in[2];
  const float* wq  = (const float*)d_in[3];
  const float* bq  = (const float*)d_in[4];
  const float* wk  = (const float*)d_in[5];
  const float* bk  = (const float*)d_in[6];
  const float* wv  = (const float*)d_in[7];
  const float* bv  = (const float*)d_in[8];
  const float* wo  = (const float*)d_in[9];
  const float* bo  = (const float*)d_in[10];
  const float* g2  = (const float*)d_in[11];
  const float* s2  = (const float*)d_in[12];
  const float* w1  = (const float*)d_in[13];
  const float* b1  = (const float*)d_in[14];
  const float* w2  = (const float*)d_in[15];
  const float* b2  = (const float*)d_in[16];
  float* out = (float*)d_out;

  char* p = (char*)d_ws;
  bf16_t* wqkvT = (bf16_t*)p;  p += (size_t)QW*Dm*2;     // + woT right after
  bf16_t* woT   = (bf16_t*)p;  p += (size_t)Dm*Dm*2;
  bf16_t* w1T   = (bf16_t*)p;  p += (size_t)FFm*Dm*2;
  bf16_t* w2T   = (bf16_t*)p;  p += (size_t)Dm*FFm*2;
  float*  bqkv  = (float*)p;   p += (size_t)QW*4;
  bf16_t* hbuf  = (bf16_t*)p;  p += (size_t)MR*Dm*2;
  bf16_t* qkv   = (bf16_t*)p;  p += (size_t)MR*QW*2;
  bf16_t* vTb   = (bf16_t*)p;  p += (size_t)32*HDm*SEQ*2;
  bf16_t* ctx   = (bf16_t*)p;  p += (size_t)MR*Dm*2;
  float*  x1    = (float*)p;   p += (size_t)MR*Dm*4;
  bf16_t* ffn1  = qkv;                  // FFN1 out: spans qkv+vTb (67.1 MB)
  float*  prj0  = (float*)qkv;
  float*  prj1  = (float*)qkv + (size_t)MR*Dm;
  float*  f2p0  = (float*)w1T;
  float*  f2p1  = (float*)wqkvT;

  wconv4<<<dim3(Dm/32, Dm/32, 4), 256, 0, stream>>>(wq, wk, wv, wo, wqkvT);
  wconv_t<<<dim3(FFm/32, Dm/32), 256, 0, stream>>>(w1, w1T, Dm, FFm);
  wconv_t<<<dim3(Dm/32, FFm/32), 256, 0, stream>>>(w2, w2T, FFm, Dm);
  bias_concat<<<dim3(Dm/256), 256, 0, stream>>>(bq, bk, bv, bqkv);

  ln_kernel<<<dim3(MR), 256, 0, stream>>>(x, g1, s1, hbuf);
  gemm8p<0><<<dim3((QW/256)*(MR/256), 1), 512, 0, stream>>>(
      hbuf, wqkvT, bqkv, qkv, nullptr, QW, Dm, Dm, QW/256);
  vtrans<<<dim3(SEQ/32, HDm/32, 32), 256, 0, stream>>>(qkv, vTb);
  flash_attn6<<<dim3(512), 256, 0, stream>>>(qkv, vTb, ctx);
  gemm8p<3><<<dim3((Dm/256)*(MR/256), 2), 512, 0, stream>>>(
      ctx, woT, nullptr, prj0, prj1, Dm, Dm/2, Dm, Dm/256);
  // fused: x1 = prj0+prj1+bo+x ; hbuf = LN2(x1)
  ln_fused<<<dim3(MR), 256, 0, stream>>>(prj0, prj1, bo, x, g2, s2, x1, hbuf);
  gemm8p<1><<<dim3((FFm/256)*(MR/256), 1), 512, 0, stream>>>(
      hbuf, w1T, b1, ffn1, nullptr, FFm, Dm, Dm, FFm/256);
  gemm8p<3><<<dim3((Dm/256)*(MR/256), 2), 512, 0, stream>>>(
      ffn1, w2T, nullptr, f2p0, f2p1, Dm, FFm/2, FFm, Dm/256);
  splitk_reduce<<<dim3(MR*Dm/1024), 256, 0, stream>>>(f2p0, f2p1, b2, x1, out, Dm);
}

// Round 17
// 663.793 us; speedup vs baseline: 1.0651x; 1.0651x over previous
//
#include <hip/hip_runtime.h>
#include <hip/hip_bf16.h>
#include <math.h>

namespace {

constexpr int Dm  = 2048;
constexpr int FFm = 8192;
constexpr int SEQ = 2048;
constexpr int HDm = 128;
constexpr int MR  = 4096;     // B*S
constexpr int QW  = 3 * Dm;   // 6144

typedef __bf16 bf16_t;
typedef __bf16 bf16x8 __attribute__((ext_vector_type(8)));
typedef float  f32x4  __attribute__((ext_vector_type(4)));

typedef __attribute__((address_space(1))) const void as1_void;
typedef __attribute__((address_space(3))) void as3_void;

__device__ __forceinline__ void gload_lds16(const void* g, void* l) {
  __builtin_amdgcn_global_load_lds((as1_void*)g, (as3_void*)l, 16, 0, 0);
}

// ---------------- LayerNorm: fp32 in -> bf16 out ----------------
__global__ __launch_bounds__(256)
void ln_kernel(const float* __restrict__ x, const float* __restrict__ sc,
               const float* __restrict__ sh, bf16_t* __restrict__ out)
{
  const int row = blockIdx.x;
  const int tid = threadIdx.x;
  const float4* xr = (const float4*)(x + (size_t)row * Dm);
  float4 v0 = xr[tid*2], v1 = xr[tid*2+1];
  float s  = v0.x+v0.y+v0.z+v0.w + v1.x+v1.y+v1.z+v1.w;
  float s2 = v0.x*v0.x+v0.y*v0.y+v0.z*v0.z+v0.w*v0.w
           + v1.x*v1.x+v1.y*v1.y+v1.z*v1.z+v1.w*v1.w;
  #pragma unroll
  for (int off = 32; off; off >>= 1) { s += __shfl_xor(s, off); s2 += __shfl_xor(s2, off); }
  __shared__ float red[8];
  if ((tid & 63) == 0) { red[(tid>>6)*2] = s; red[(tid>>6)*2+1] = s2; }
  __syncthreads();
  s  = red[0]+red[2]+red[4]+red[6];
  s2 = red[1]+red[3]+red[5]+red[7];
  const float mean = s * (1.f/Dm);
  const float var  = fmaxf(s2 * (1.f/Dm) - mean*mean, 0.f);
  const float rstd = rsqrtf(var + 1e-5f);
  const float4* scp = (const float4*)sc;
  const float4* shp = (const float4*)sh;
  float4 sc0 = scp[tid*2], sc1 = scp[tid*2+1];
  float4 sh0 = shp[tid*2], sh1 = shp[tid*2+1];
  __attribute__((aligned(16))) bf16_t ob[8];
  ob[0] = (bf16_t)((v0.x-mean)*rstd*sc0.x + sh0.x);
  ob[1] = (bf16_t)((v0.y-mean)*rstd*sc0.y + sh0.y);
  ob[2] = (bf16_t)((v0.z-mean)*rstd*sc0.z + sh0.z);
  ob[3] = (bf16_t)((v0.w-mean)*rstd*sc0.w + sh0.w);
  ob[4] = (bf16_t)((v1.x-mean)*rstd*sc1.x + sh1.x);
  ob[5] = (bf16_t)((v1.y-mean)*rstd*sc1.y + sh1.y);
  ob[6] = (bf16_t)((v1.z-mean)*rstd*sc1.z + sh1.z);
  ob[7] = (bf16_t)((v1.w-mean)*rstd*sc1.w + sh1.w);
  *(uint4*)(out + (size_t)row*Dm + tid*8) = *(const uint4*)ob;
}

// -- fused: v = p0+p1+bias+resid; x1 = v (f32); out = LN(v) (bf16) --
__global__ __launch_bounds__(256)
void ln_fused(const float* __restrict__ p0, const float* __restrict__ p1,
              const float* __restrict__ bias, const float* __restrict__ resid,
              const float* __restrict__ sc, const float* __restrict__ sh,
              float* __restrict__ x1, bf16_t* __restrict__ out)
{
  const int row = blockIdx.x;
  const int tid = threadIdx.x;
  const size_t base = (size_t)row * Dm + tid*8;
  float v[8];
  #pragma unroll
  for (int hh = 0; hh < 2; ++hh) {
    float4 a  = *(const float4*)(p0 + base + hh*4);
    float4 b  = *(const float4*)(p1 + base + hh*4);
    float4 r  = *(const float4*)(resid + base + hh*4);
    float4 bv = *(const float4*)(bias + tid*8 + hh*4);
    v[hh*4+0] = a.x + b.x + bv.x + r.x;
    v[hh*4+1] = a.y + b.y + bv.y + r.y;
    v[hh*4+2] = a.z + b.z + bv.z + r.z;
    v[hh*4+3] = a.w + b.w + bv.w + r.w;
  }
  *(float4*)(x1 + base)     = *(const float4*)&v[0];
  *(float4*)(x1 + base + 4) = *(const float4*)&v[4];
  float s = 0.f, s2 = 0.f;
  #pragma unroll
  for (int j = 0; j < 8; ++j) { s += v[j]; s2 += v[j]*v[j]; }
  #pragma unroll
  for (int off = 32; off; off >>= 1) { s += __shfl_xor(s, off); s2 += __shfl_xor(s2, off); }
  __shared__ float red[8];
  if ((tid & 63) == 0) { red[(tid>>6)*2] = s; red[(tid>>6)*2+1] = s2; }
  __syncthreads();
  s  = red[0]+red[2]+red[4]+red[6];
  s2 = red[1]+red[3]+red[5]+red[7];
  const float mean = s * (1.f/Dm);
  const float var  = fmaxf(s2 * (1.f/Dm) - mean*mean, 0.f);
  const float rstd = rsqrtf(var + 1e-5f);
  __attribute__((aligned(16))) bf16_t ob[8];
  #pragma unroll
  for (int hh = 0; hh < 2; ++hh) {
    float4 scv = *(const float4*)(sc + tid*8 + hh*4);
    float4 shv = *(const float4*)(sh + tid*8 + hh*4);
    ob[hh*4+0] = (bf16_t)((v[hh*4+0]-mean)*rstd*scv.x + shv.x);
    ob[hh*4+1] = (bf16_t)((v[hh*4+1]-mean)*rstd*scv.y + shv.y);
    ob[hh*4+2] = (bf16_t)((v[hh*4+2]-mean)*rstd*scv.z + shv.z);
    ob[hh*4+3] = (bf16_t)((v[hh*4+3]-mean)*rstd*scv.w + shv.w);
  }
  *(uint4*)(out + base) = *(const uint4*)ob;
}

// ----- weights q,k,v,o (each [Dm][Dm] fp32) -> bf16 transposed, packed -----
__global__ __launch_bounds__(256)
void wconv4(const float* __restrict__ wq, const float* __restrict__ wk,
            const float* __restrict__ wv, const float* __restrict__ wo,
            bf16_t* __restrict__ dst)
{
  const int z = blockIdx.z;
  const float* W = (z == 0) ? wq : (z == 1) ? wk : (z == 2) ? wv : wo;
  bf16_t* WT = dst + (size_t)z * Dm * Dm;
  __shared__ float tile[32][33];
  const int tx = threadIdx.x & 31, ty = threadIdx.x >> 5;
  const int nb = blockIdx.x * 32, kb = blockIdx.y * 32;
  #pragma unroll
  for (int p = 0; p < 4; ++p)
    tile[ty+8*p][tx] = W[(size_t)(kb+ty+8*p)*Dm + nb + tx];
  __syncthreads();
  #pragma unroll
  for (int p = 0; p < 4; ++p)
    WT[(size_t)(nb+ty+8*p)*Dm + kb + tx] = (bf16_t)tile[tx][ty+8*p];
}

// ------------- weight fp32 [K][N] -> bf16 transposed [N][K] -------------
__global__ __launch_bounds__(256)
void wconv_t(const float* __restrict__ W, bf16_t* __restrict__ WT, int K, int N)
{
  __shared__ float tile[32][33];
  const int tx = threadIdx.x & 31, ty = threadIdx.x >> 5;
  const int nb = blockIdx.x * 32, kb = blockIdx.y * 32;
  #pragma unroll
  for (int p = 0; p < 4; ++p)
    tile[ty+8*p][tx] = W[(size_t)(kb+ty+8*p)*N + nb + tx];
  __syncthreads();
  #pragma unroll
  for (int p = 0; p < 4; ++p)
    WT[(size_t)(nb+ty+8*p)*K + kb + tx] = (bf16_t)tile[tx][ty+8*p];
}

__global__ void bias_concat(const float* __restrict__ bq, const float* __restrict__ bk,
                            const float* __restrict__ bv, float* __restrict__ o)
{
  int i = blockIdx.x*256 + threadIdx.x;
  o[i] = bq[i]; o[Dm+i] = bk[i]; o[2*Dm+i] = bv[i];
}

// ----- V slice of qkv [B*S][6144] -> vT [B*H][128][2048] (bf16) -----
__global__ __launch_bounds__(256)
void vtrans(const bf16_t* __restrict__ qkv, bf16_t* __restrict__ vT)
{
  __shared__ bf16_t tile[32][33];
  const int tx = threadIdx.x & 31, ty = threadIdx.x >> 5;
  const int s0 = blockIdx.x*32, d0 = blockIdx.y*32, bh = blockIdx.z;
  const int b = bh >> 4, h = bh & 15;
  const bf16_t* src = qkv + (size_t)(b*SEQ)*QW + 2*Dm + h*HDm;
  #pragma unroll
  for (int p = 0; p < 4; ++p)
    tile[ty+8*p][tx] = src[(size_t)(s0+ty+8*p)*QW + d0 + tx];
  __syncthreads();
  bf16_t* dst = vT + (size_t)bh*HDm*SEQ;
  #pragma unroll
  for (int p = 0; p < 4; ++p)
    dst[(size_t)(d0+ty+8*p)*SEQ + s0 + tx] = tile[tx][ty+8*p];
}

// ---- GEMM 256x256, 8-phase, 2 K-tiles(BK=64)/iter, 8 waves (2Mx4N) ----
// MODE: 0 bf16+bias | 1 bf16+bias+GELU | 3 f32 raw partial (split-K)
template<int MODE>
__global__ __launch_bounds__(512, 2)
void gemm8p(const bf16_t* __restrict__ A, const bf16_t* __restrict__ BT,
            const float* __restrict__ bias,
            void* __restrict__ Cout, void* __restrict__ Cout2,
            int Ndim, int Kslice, int Kstride, int gn)
{
  // 2D XCD chunking: 2x4 chunk grid; chunk = bid&7 (XCD-pinned)
  const int gm = (int)gridDim.x / gn;
  const int cm = gm >> 1, cn = gn >> 2;
  const int c = blockIdx.x & 7;
  const int idx = blockIdx.x >> 3;
  const int mi = idx / cn, ni = idx - mi*cn;
  const int m0 = ((c >> 2)*cm + mi) * 256;
  const int n0 = ((c & 3)*cn + ni) * 256;
  const int kOff = blockIdx.y * Kslice;
  const int tid = threadIdx.x;
  const int lane = tid & 63;
  const int w = tid >> 6;
  const int wr = w >> 2, wc = w & 3;              // 2 x 4 waves
  const int lr = lane & 15, kg = lane >> 4;

  // 8 regions of 8192 elems: buf0{r0:A-h0, r1:A-h1, r2:B-h0, r3:B-h1} buf1{r4..r7}
  __shared__ __attribute__((aligned(16))) bf16_t lds[65536];

  f32x4 acc[8][4] = {};

  // --- staging: 4 streams, incremental pointers (+64 elems per call) ---
  const int r1   = tid >> 3;
  const int blk1 = (tid & 7) ^ (r1 & 7);
  const size_t rowoff = (size_t)64 * Kstride;
  const bf16_t* pA0 = A  + (size_t)(m0 + r1)*Kstride       + kOff + blk1*8;
  const bf16_t* pA1 = A  + (size_t)(m0 + 128 + r1)*Kstride + kOff + blk1*8;
  const bf16_t* pB0 = BT + (size_t)(n0 + r1)*Kstride       + kOff + blk1*8;
  const bf16_t* pB1 = BT + (size_t)(n0 + 128 + r1)*Kstride + kOff + blk1*8;
  bf16_t* const d0 = lds + (size_t)tid*8;

#define STG(p, region) do { \
    gload_lds16((p), d0 + (size_t)(region)*8192); \
    gload_lds16((p) + rowoff, d0 + (size_t)(region)*8192 + 4096); \
    (p) += 64; } while (0)

  // read A-half mh: rows wr*64 + ml*16 + lr within region (buf*4 + mh)
  auto readA = [&](int buf, int mh, bf16x8* f) {
    #pragma unroll
    for (int ml = 0; ml < 4; ++ml)
      #pragma unroll
      for (int kk = 0; kk < 2; ++kk) {
        const bf16_t* base = lds + (buf*4 + mh)*8192;
        const int row = wr*64 + ml*16 + lr;
        f[ml*2+kk] = *(const bf16x8*)(base + row*64 + (((kk*4+kg) ^ (row&7))*8));
      }
  };
  // read B-half nh: rows wc*32 + nl*16 + lr within region (buf*4 + 2 + nh)
  auto readB = [&](int buf, int nh, bf16x8* f) {
    #pragma unroll
    for (int nl = 0; nl < 2; ++nl)
      #pragma unroll
      for (int kk = 0; kk < 2; ++kk) {
        const bf16_t* base = lds + (buf*4 + 2 + nh)*8192;
        const int row = wc*32 + nl*16 + lr;
        f[nl*2+kk] = *(const bf16x8*)(base + row*64 + (((kk*4+kg) ^ (row&7))*8));
      }
  };
  auto mfma16 = [&](int mh, int nh, const bf16x8* Af, const bf16x8* Bf) {
    __builtin_amdgcn_s_setprio(1);
    #pragma unroll
    for (int ml = 0; ml < 4; ++ml)
      #pragma unroll
      for (int nl = 0; nl < 2; ++nl)
        #pragma unroll
        for (int kk = 0; kk < 2; ++kk)
          acc[mh*4+ml][nh*2+nl] =
            __builtin_amdgcn_mfma_f32_16x16x32_bf16(Af[ml*2+kk], Bf[nl*2+kk],
                                                    acc[mh*4+ml][nh*2+nl], 0, 0, 0);
    __builtin_amdgcn_s_setprio(0);
  };

#define BAR() __builtin_amdgcn_s_barrier()
#define LGKM0() asm volatile("s_waitcnt lgkmcnt(0)")

  bf16x8 Af0[8], Af1[8], Bf0[4], Bf1[4];      // even K-tile set
  bf16x8 Af0b[8], Af1b[8], Bf0b[4], Bf1b[4];  // odd K-tile set

  // prologue: stage t0 (r0-r3) then t1 (r4-r7); vmcnt(8) -> t0 resident.
  STG(pA0, 0); STG(pA1, 1); STG(pB0, 2); STG(pB1, 3);
  STG(pA0, 4); STG(pA1, 5); STG(pB0, 6); STG(pB1, 7);
  asm volatile("s_waitcnt vmcnt(8)" ::: "memory");
  BAR();

  const int NITER = Kslice >> 7;     // iterations of 2 K-tiles
  for (int j = 0; j < NITER; ++j) {
    const bool s2 = (j + 1 < NITER);

    // P1: reads r0 (A-h0 t0) + r2 (B-h0 t0); no stage
    readA(0, 0, Af0); readB(0, 0, Bf0);
    BAR(); LGKM0(); mfma16(0, 0, Af0, Bf0); BAR();

    // P2: reads r3 (B-h1 t0); stage r0 <- A-h0(t0+2)   [r0 last read P1]
    readB(0, 1, Bf1);
    if (s2) STG(pA0, 0);
    BAR(); LGKM0(); mfma16(0, 1, Af0, Bf1); BAR();

    // P3: reads r1 (A-h1 t0); stage r2 <- B-h0(t0+2)   [r2 last read P1]
    readA(0, 1, Af1);
    if (s2) STG(pB0, 2);
    BAR(); LGKM0(); mfma16(1, 1, Af1, Bf1);
    if (s2) asm volatile("s_waitcnt vmcnt(4)" ::: "memory");
    else    asm volatile("s_waitcnt vmcnt(0)" ::: "memory");
    BAR();

    // P4: reads r4 (A-h0 t1); stage r1 <- A-h1(t0+2), r3 <- B-h1(t0+2)
    readA(1, 0, Af0b);
    if (s2) { STG(pA1, 1); STG(pB1, 3); }
    BAR(); LGKM0(); mfma16(1, 0, Af1, Bf0); BAR();

    // P5: reads r6 (B-h0 t1); no stage
    readB(1, 0, Bf0b);
    BAR(); LGKM0(); mfma16(0, 0, Af0b, Bf0b); BAR();

    // P6: reads r7 (B-h1 t1); stage r4 <- A-h0(t1+2), r6 <- B-h0(t1+2)
    readB(1, 1, Bf1b);
    if (s2) { STG(pA0, 4); STG(pB0, 6); }
    BAR(); LGKM0(); mfma16(0, 1, Af0b, Bf1b); BAR();

    // P7: reads r5 (A-h1 t1); stage r7 <- B-h1(t1+2)   [r7 last read P6]
    readA(1, 1, Af1b);
    if (s2) STG(pB1, 7);
    BAR(); LGKM0(); mfma16(1, 1, Af1b, Bf1b); BAR();

    // P8: stage r5 <- A-h1(t1+2)                       [r5 last read P7]
    if (s2) STG(pA1, 5);
    BAR(); mfma16(1, 0, Af1b, Bf0b);
    if (s2) asm volatile("s_waitcnt vmcnt(8)" ::: "memory");
    else    asm volatile("s_waitcnt vmcnt(0)" ::: "memory");
    BAR();
  }
#undef STG
#undef BAR
#undef LGKM0

  // ---- epilogue ----
  // row(MF) = (MF>>2)*128 + wr*64 + (MF&3)*16 + kg*4 + jj
  // col(NF) = (NF>>1)*128 + wc*32 + (NF&1)*16 + lr
  if constexpr (MODE == 0 || MODE == 1) {
    __syncthreads();
    #pragma unroll
    for (int NF = 0; NF < 4; ++NF) {
      const int col = (NF>>1)*128 + wc*32 + (NF&1)*16 + lr;
      const float bv = bias[n0 + col];
      #pragma unroll
      for (int MF = 0; MF < 8; ++MF) {
        #pragma unroll
        for (int jj = 0; jj < 4; ++jj) {
          float v = acc[MF][NF][jj] + bv;
          if constexpr (MODE == 1) v = 0.5f*v*(1.f + erff(v*0.70710678118f));
          const int row = (MF>>2)*128 + wr*64 + (MF&3)*16 + kg*4 + jj;
          const int adr = row*256 + (((col >> 3) ^ (row & 7)) << 3) + (col & 7);
          lds[adr] = (bf16_t)v;
        }
      }
    }
    __syncthreads();
    bf16_t* outp = (bf16_t*)Cout;
    #pragma unroll
    for (int i = 0; i < 16; ++i) {
      const int s = tid + i*512;
      const int row = s >> 5, ch = s & 31;
      uint4 vv = *(const uint4*)(lds + row*256 + ((ch ^ (row & 7)) << 3));
      *(uint4*)(outp + (size_t)(m0 + row)*Ndim + n0 + ch*8) = vv;
    }
  } else {
    float* pout = (float*)(blockIdx.y ? Cout2 : Cout);
    #pragma unroll
    for (int NF = 0; NF < 4; ++NF) {
      const int col = n0 + (NF>>1)*128 + wc*32 + (NF&1)*16 + lr;
      #pragma unroll
      for (int MF = 0; MF < 8; ++MF) {
        const int rbase = m0 + (MF>>2)*128 + wr*64 + (MF&3)*16 + kg*4;
        #pragma unroll
        for (int jj = 0; jj < 4; ++jj)
          pout[(size_t)(rbase + jj)*Ndim + col] = acc[MF][NF][jj];
      }
    }
  }
}

// ---- split-K reduce: out = p0 + p1 + bias + resid (f32, Ndim pow2) ----
__global__ __launch_bounds__(256)
void splitk_reduce(const float* __restrict__ p0, const float* __restrict__ p1,
                   const float* __restrict__ bias, const float* __restrict__ resid,
                   float* __restrict__ out, int Ndim)
{
  const size_t e = ((size_t)blockIdx.x*256 + threadIdx.x) * 4;
  float4 a = *(const float4*)(p0 + e);
  float4 b = *(const float4*)(p1 + e);
  float4 r = *(const float4*)(resid + e);
  float4 bv = *(const float4*)(bias + (int)(e & (size_t)(Ndim - 1)));
  float4 o;
  o.x = a.x + b.x + bv.x + r.x;
  o.y = a.y + b.y + bv.y + r.y;
  o.z = a.z + b.z + bv.z + r.z;
  o.w = a.w + b.w + bv.w + r.w;
  *(float4*)(out + e) = o;
}

// ------- causal flash attention v5: fused balanced pair, 8 waves -------
// 256 blocks x 512 thr. Waves 0-3 own q-tile pr, waves 4-7 own 15-pr
// (128 rows each); one shared K/V staging stream over the union range.
__global__ __launch_bounds__(512)
void flash_attn5(const bf16_t* __restrict__ qkv, const bf16_t* __restrict__ vT,
                 bf16_t* __restrict__ ctx)
{
  const int bid = blockIdx.x;                  // 0..255
  const int bh  = (bid & 7) + 8 * ((bid >> 3) & 3);  // XCD-pinned head
  const int pr  = bid >> 5;                    // 0..7 pair index
  const int b = bh >> 4, h = bh & 15;
  const int tid = threadIdx.x;
  const int lane = tid & 63;
  const int w = tid >> 6;                      // 0..7
  const int wg = w >> 2;                       // 0: qi=pr, 1: qi=15-pr
  const int wsub = w & 3;
  const int lr = lane & 15, kg = lane >> 4;

  const int qi = wg ? (15 - pr) : pr;
  const int Q0 = qi * 128;
  const int q0w = Q0 + wsub * 32;

  __shared__ __attribute__((aligned(16))) bf16_t Ks[64*128];
  __shared__ __attribute__((aligned(16))) bf16_t Vs[128*64];
  __shared__ __attribute__((aligned(16))) bf16_t Plds[8*2048];

  const bf16_t* kbase = qkv + (size_t)(b*SEQ)*QW + Dm + h*HDm;
  const bf16_t* vbase = vT + (size_t)bh*HDm*SEQ;
  const float scl = 0.08838834764831845f * 1.44269504089f; // 1/sqrt(128)*log2(e)

  auto stage = [&](int k0) {
    #pragma unroll
    for (int i = 0; i < 2; ++i) {
      const int s = tid + i*512;                 // K slot (1024 total)
      const int row = s >> 4, sl = s & 15;
      gload_lds16(kbase + (size_t)(k0 + row)*QW + (sl ^ (row & 7))*8, Ks + s*8);
    }
    #pragma unroll
    for (int i = 0; i < 2; ++i) {
      const int s = tid + i*512;                 // V slot (1024 total)
      const int row = s >> 3, sl = s & 7;
      gload_lds16(vbase + (size_t)row*SEQ + k0 + (sl ^ (row & 7))*8, Vs + s*8);
    }
  };

  bf16x8 qf[2][4];
  #pragma unroll
  for (int rt = 0; rt < 2; ++rt) {
    const bf16_t* qb = qkv + (size_t)(b*SEQ + q0w + rt*16 + lr)*QW + h*HDm;
    #pragma unroll
    for (int g = 0; g < 4; ++g)
      qf[rt][g] = *(const bf16x8*)(qb + g*32 + kg*8);
  }

  float mrow[2][4], lsum[2][4];
  f32x4 oacc[2][8];
  #pragma unroll
  for (int rt = 0; rt < 2; ++rt) {
    #pragma unroll
    for (int j = 0; j < 4; ++j) { mrow[rt][j] = -INFINITY; lsum[rt][j] = 0.f; }
    #pragma unroll
    for (int dt = 0; dt < 8; ++dt) oacc[rt][dt] = (f32x4){0.f,0.f,0.f,0.f};
  }

  const int NT = (16 - pr) * 2;                // union k-range of the pair
  stage(0);
  for (int t = 0; t < NT; ++t) {
    const int k0 = t * 64;
    __syncthreads();                             // staging complete
    if (k0 < q0w + 32) {
      f32x4 sa[2][4];
      #pragma unroll
      for (int rt = 0; rt < 2; ++rt)
        #pragma unroll
        for (int ct = 0; ct < 4; ++ct) sa[rt][ct] = (f32x4){0.f,0.f,0.f,0.f};
      #pragma unroll
      for (int ct = 0; ct < 4; ++ct) {
        const int krow = ct*16 + lr;
        #pragma unroll
        for (int g = 0; g < 4; ++g) {
          bf16x8 kf = *(const bf16x8*)(Ks + krow*128 + ((4*g + kg) ^ (krow & 7))*8);
          sa[0][ct] = __builtin_amdgcn_mfma_f32_16x16x32_bf16(qf[0][g], kf, sa[0][ct], 0, 0, 0);
          sa[1][ct] = __builtin_amdgcn_mfma_f32_16x16x32_bf16(qf[1][g], kf, sa[1][ct], 0, 0, 0);
        }
      }
      #pragma unroll
      for (int rt = 0; rt < 2; ++rt)
        #pragma unroll
        for (int ct = 0; ct < 4; ++ct)
          #pragma unroll
          for (int j = 0; j < 4; ++j) sa[rt][ct][j] *= scl;
      if (k0 + 63 > q0w) {
        #pragma unroll
        for (int ct = 0; ct < 4; ++ct) {
          const int kidx = k0 + ct*16 + lr;
          #pragma unroll
          for (int rt = 0; rt < 2; ++rt)
            #pragma unroll
            for (int j = 0; j < 4; ++j) {
              const int qidx = q0w + rt*16 + kg*4 + j;
              if (kidx > qidx) sa[rt][ct][j] = -INFINITY;
            }
        }
      }
      #pragma unroll
      for (int rt = 0; rt < 2; ++rt) {
        #pragma unroll
        for (int j = 0; j < 4; ++j) {
          const int prow = kg*4 + j;
          float x0 = sa[rt][0][j], x1 = sa[rt][1][j], x2 = sa[rt][2][j], x3 = sa[rt][3][j];
          float v = fmaxf(fmaxf(x0, x1), fmaxf(x2, x3));
          v = fmaxf(v, __shfl_xor(v, 1));
          v = fmaxf(v, __shfl_xor(v, 2));
          v = fmaxf(v, __shfl_xor(v, 4));
          v = fmaxf(v, __shfl_xor(v, 8));
          const float mn = fmaxf(mrow[rt][j], v);
          const float alpha = exp2f(mrow[rt][j] - mn);
          mrow[rt][j] = mn;
          float p0 = exp2f(x0 - mn), p1 = exp2f(x1 - mn);
          float p2 = exp2f(x2 - mn), p3 = exp2f(x3 - mn);
          float ss = (p0 + p1) + (p2 + p3);
          ss += __shfl_xor(ss, 1);
          ss += __shfl_xor(ss, 2);
          ss += __shfl_xor(ss, 4);
          ss += __shfl_xor(ss, 8);
          lsum[rt][j] = lsum[rt][j]*alpha + ss;
          #pragma unroll
          for (int dt = 0; dt < 8; ++dt) oacc[rt][dt][j] *= alpha;
          const int base = w*2048 + rt*1024 + prow*64;
          const int sw = (prow & 7) << 3;
          Plds[(base + ( 0 + lr)) ^ sw] = (bf16_t)p0;
          Plds[(base + (16 + lr)) ^ sw] = (bf16_t)p1;
          Plds[(base + (32 + lr)) ^ sw] = (bf16_t)p2;
          Plds[(base + (48 + lr)) ^ sw] = (bf16_t)p3;
        }
      }
      bf16x8 pf[2][2];
      {
        const int sw = (lr & 7) << 3;
        #pragma unroll
        for (int rt = 0; rt < 2; ++rt) {
          pf[rt][0] = *(const bf16x8*)(Plds + ((w*2048 + rt*1024 + lr*64 +      kg*8) ^ sw));
          pf[rt][1] = *(const bf16x8*)(Plds + ((w*2048 + rt*1024 + lr*64 + 32 + kg*8) ^ sw));
        }
      }
      #pragma unroll
      for (int dt = 0; dt < 8; ++dt) {
        const int vrow = dt*16 + lr;
        #pragma unroll
        for (int kc = 0; kc < 2; ++kc) {
          bf16x8 vf = *(const bf16x8*)(Vs + vrow*64 + ((4*kc + kg) ^ (vrow & 7))*8);
          oacc[0][dt] = __builtin_amdgcn_mfma_f32_16x16x32_bf16(pf[0][kc], vf, oacc[0][dt], 0, 0, 0);
          oacc[1][dt] = __builtin_amdgcn_mfma_f32_16x16x32_bf16(pf[1][kc], vf, oacc[1][dt], 0, 0, 0);
        }
      }
    }
    __syncthreads();                             // all reads of Ks/Vs done
    if (t + 1 < NT) stage((t + 1) * 64);
  }

  #pragma unroll
  for (int rt = 0; rt < 2; ++rt) {
    bf16_t* cb = ctx + (size_t)(b*SEQ + q0w + rt*16 + kg*4)*Dm + h*HDm;
    #pragma unroll
    for (int j = 0; j < 4; ++j) {
      const float inv = 1.f / lsum[rt][j];
      #pragma unroll
      for (int dt = 0; dt < 8; ++dt)
        cb[(size_t)j*Dm + dt*16 + lr] = (bf16_t)(oacc[rt][dt][j] * inv);
    }
  }
}

} // namespace

extern "C" void kernel_launch(void* const* d_in, const int* in_sizes, int n_in,
                              void* d_out, int out_size, void* d_ws, size_t ws_size,
                              hipStream_t stream)
{
  const float* x   = (const float*)d_in[0];
  const float* g1  = (const float*)d_in[1];
  const float* s1  = (const float*)d_in[2];
  const float* wq  = (const float*)d_in[3];
  const float* bq  = (const float*)d_in[4];
  const float* wk  = (const float*)d_in[5];
  const float* bk  = (const float*)d_in[6];
  const float* wv  = (const float*)d_in[7];
  const float* bv  = (const float*)d_in[8];
  const float* wo  = (const float*)d_in[9];
  const float* bo  = (const float*)d_in[10];
  const float* g2  = (const float*)d_in[11];
  const float* s2  = (const float*)d_in[12];
  const float* w1  = (const float*)d_in[13];
  const float* b1  = (const float*)d_in[14];
  const float* w2  = (const float*)d_in[15];
  const float* b2  = (const float*)d_in[16];
  float* out = (float*)d_out;

  char* p = (char*)d_ws;
  bf16_t* wqkvT = (bf16_t*)p;  p += (size_t)QW*Dm*2;     // + woT right after
  bf16_t* woT   = (bf16_t*)p;  p += (size_t)Dm*Dm*2;
  bf16_t* w1T   = (bf16_t*)p;  p += (size_t)FFm*Dm*2;
  bf16_t* w2T   = (bf16_t*)p;  p += (size_t)Dm*FFm*2;
  float*  bqkv  = (float*)p;   p += (size_t)QW*4;
  bf16_t* hbuf  = (bf16_t*)p;  p += (size_t)MR*Dm*2;
  bf16_t* qkv   = (bf16_t*)p;  p += (size_t)MR*QW*2;
  bf16_t* vTb   = (bf16_t*)p;  p += (size_t)32*HDm*SEQ*2;
  bf16_t* ctx   = (bf16_t*)p;  p += (size_t)MR*Dm*2;
  float*  x1    = (float*)p;   p += (size_t)MR*Dm*4;
  bf16_t* ffn1  = qkv;                  // FFN1 out: spans qkv+vTb (67.1 MB)
  float*  prj0  = (float*)qkv;
  float*  prj1  = (float*)qkv + (size_t)MR*Dm;
  float*  f2p0  = (float*)w1T;
  float*  f2p1  = (float*)wqkvT;

  wconv4<<<dim3(Dm/32, Dm/32, 4), 256, 0, stream>>>(wq, wk, wv, wo, wqkvT);
  wconv_t<<<dim3(FFm/32, Dm/32), 256, 0, stream>>>(w1, w1T, Dm, FFm);
  wconv_t<<<dim3(Dm/32, FFm/32), 256, 0, stream>>>(w2, w2T, FFm, Dm);
  bias_concat<<<dim3(Dm/256), 256, 0, stream>>>(bq, bk, bv, bqkv);

  ln_kernel<<<dim3(MR), 256, 0, stream>>>(x, g1, s1, hbuf);
  gemm8p<0><<<dim3((QW/256)*(MR/256), 1), 512, 0, stream>>>(
      hbuf, wqkvT, bqkv, qkv, nullptr, QW, Dm, Dm, QW/256);
  vtrans<<<dim3(SEQ/32, HDm/32, 32), 256, 0, stream>>>(qkv, vTb);
  flash_attn5<<<dim3(256), 512, 0, stream>>>(qkv, vTb, ctx);
  gemm8p<3><<<dim3((Dm/256)*(MR/256), 2), 512, 0, stream>>>(
      ctx, woT, nullptr, prj0, prj1, Dm, Dm/2, Dm, Dm/256);
  // fused: x1 = prj0+prj1+bo+x ; hbuf = LN2(x1)
  ln_fused<<<dim3(MR), 256, 0, stream>>>(prj0, prj1, bo, x, g2, s2, x1, hbuf);
  gemm8p<1><<<dim3((FFm/256)*(MR/256), 1), 512, 0, stream>>>(
      hbuf, w1T, b1, ffn1, nullptr, FFm, Dm, Dm, FFm/256);
  gemm8p<3><<<dim3((Dm/256)*(MR/256), 2), 512, 0, stream>>>(
      ffn1, w2T, nullptr, f2p0, f2p1, Dm, FFm/2, FFm, Dm/256);
  splitk_reduce<<<dim3(MR*Dm/1024), 256, 0, stream>>>(f2p0, f2p1, b2, x1, out, Dm);
}

// Round 18
// 659.589 us; speedup vs baseline: 1.0719x; 1.0064x over previous
//
#include <hip/hip_runtime.h>
#include <hip/hip_bf16.h>
#include <math.h>

namespace {

constexpr int Dm  = 2048;
constexpr int FFm = 8192;
constexpr int SEQ = 2048;
constexpr int HDm = 128;
constexpr int MR  = 4096;     // B*S
constexpr int QW  = 3 * Dm;   // 6144

typedef __bf16 bf16_t;
typedef __bf16 bf16x8 __attribute__((ext_vector_type(8)));
typedef float  f32x4  __attribute__((ext_vector_type(4)));

typedef __attribute__((address_space(1))) const void as1_void;
typedef __attribute__((address_space(3))) void as3_void;

__device__ __forceinline__ void gload_lds16(const void* g, void* l) {
  __builtin_amdgcn_global_load_lds((as1_void*)g, (as3_void*)l, 16, 0, 0);
}

// ---------------- LayerNorm: fp32 in -> bf16 out ----------------
__global__ __launch_bounds__(256)
void ln_kernel(const float* __restrict__ x, const float* __restrict__ sc,
               const float* __restrict__ sh, bf16_t* __restrict__ out)
{
  const int row = blockIdx.x;
  const int tid = threadIdx.x;
  const float4* xr = (const float4*)(x + (size_t)row * Dm);
  float4 v0 = xr[tid*2], v1 = xr[tid*2+1];
  float s  = v0.x+v0.y+v0.z+v0.w + v1.x+v1.y+v1.z+v1.w;
  float s2 = v0.x*v0.x+v0.y*v0.y+v0.z*v0.z+v0.w*v0.w
           + v1.x*v1.x+v1.y*v1.y+v1.z*v1.z+v1.w*v1.w;
  #pragma unroll
  for (int off = 32; off; off >>= 1) { s += __shfl_xor(s, off); s2 += __shfl_xor(s2, off); }
  __shared__ float red[8];
  if ((tid & 63) == 0) { red[(tid>>6)*2] = s; red[(tid>>6)*2+1] = s2; }
  __syncthreads();
  s  = red[0]+red[2]+red[4]+red[6];
  s2 = red[1]+red[3]+red[5]+red[7];
  const float mean = s * (1.f/Dm);
  const float var  = fmaxf(s2 * (1.f/Dm) - mean*mean, 0.f);
  const float rstd = rsqrtf(var + 1e-5f);
  const float4* scp = (const float4*)sc;
  const float4* shp = (const float4*)sh;
  float4 sc0 = scp[tid*2], sc1 = scp[tid*2+1];
  float4 sh0 = shp[tid*2], sh1 = shp[tid*2+1];
  __attribute__((aligned(16))) bf16_t ob[8];
  ob[0] = (bf16_t)((v0.x-mean)*rstd*sc0.x + sh0.x);
  ob[1] = (bf16_t)((v0.y-mean)*rstd*sc0.y + sh0.y);
  ob[2] = (bf16_t)((v0.z-mean)*rstd*sc0.z + sh0.z);
  ob[3] = (bf16_t)((v0.w-mean)*rstd*sc0.w + sh0.w);
  ob[4] = (bf16_t)((v1.x-mean)*rstd*sc1.x + sh1.x);
  ob[5] = (bf16_t)((v1.y-mean)*rstd*sc1.y + sh1.y);
  ob[6] = (bf16_t)((v1.z-mean)*rstd*sc1.z + sh1.z);
  ob[7] = (bf16_t)((v1.w-mean)*rstd*sc1.w + sh1.w);
  *(uint4*)(out + (size_t)row*Dm + tid*8) = *(const uint4*)ob;
}

// -- fused: v = p0+p1+bias+resid; x1 = v (f32); out = LN(v) (bf16) --
__global__ __launch_bounds__(256)
void ln_fused(const float* __restrict__ p0, const float* __restrict__ p1,
              const float* __restrict__ bias, const float* __restrict__ resid,
              const float* __restrict__ sc, const float* __restrict__ sh,
              float* __restrict__ x1, bf16_t* __restrict__ out)
{
  const int row = blockIdx.x;
  const int tid = threadIdx.x;
  const size_t base = (size_t)row * Dm + tid*8;
  float v[8];
  #pragma unroll
  for (int hh = 0; hh < 2; ++hh) {
    float4 a  = *(const float4*)(p0 + base + hh*4);
    float4 b  = *(const float4*)(p1 + base + hh*4);
    float4 r  = *(const float4*)(resid + base + hh*4);
    float4 bv = *(const float4*)(bias + tid*8 + hh*4);
    v[hh*4+0] = a.x + b.x + bv.x + r.x;
    v[hh*4+1] = a.y + b.y + bv.y + r.y;
    v[hh*4+2] = a.z + b.z + bv.z + r.z;
    v[hh*4+3] = a.w + b.w + bv.w + r.w;
  }
  *(float4*)(x1 + base)     = *(const float4*)&v[0];
  *(float4*)(x1 + base + 4) = *(const float4*)&v[4];
  float s = 0.f, s2 = 0.f;
  #pragma unroll
  for (int j = 0; j < 8; ++j) { s += v[j]; s2 += v[j]*v[j]; }
  #pragma unroll
  for (int off = 32; off; off >>= 1) { s += __shfl_xor(s, off); s2 += __shfl_xor(s2, off); }
  __shared__ float red[8];
  if ((tid & 63) == 0) { red[(tid>>6)*2] = s; red[(tid>>6)*2+1] = s2; }
  __syncthreads();
  s  = red[0]+red[2]+red[4]+red[6];
  s2 = red[1]+red[3]+red[5]+red[7];
  const float mean = s * (1.f/Dm);
  const float var  = fmaxf(s2 * (1.f/Dm) - mean*mean, 0.f);
  const float rstd = rsqrtf(var + 1e-5f);
  __attribute__((aligned(16))) bf16_t ob[8];
  #pragma unroll
  for (int hh = 0; hh < 2; ++hh) {
    float4 scv = *(const float4*)(sc + tid*8 + hh*4);
    float4 shv = *(const float4*)(sh + tid*8 + hh*4);
    ob[hh*4+0] = (bf16_t)((v[hh*4+0]-mean)*rstd*scv.x + shv.x);
    ob[hh*4+1] = (bf16_t)((v[hh*4+1]-mean)*rstd*scv.y + shv.y);
    ob[hh*4+2] = (bf16_t)((v[hh*4+2]-mean)*rstd*scv.z + shv.z);
    ob[hh*4+3] = (bf16_t)((v[hh*4+3]-mean)*rstd*scv.w + shv.w);
  }
  *(uint4*)(out + base) = *(const uint4*)ob;
}

// ----- weights q,k,v,o (each [Dm][Dm] fp32) -> bf16 transposed, packed -----
__global__ __launch_bounds__(256)
void wconv4(const float* __restrict__ wq, const float* __restrict__ wk,
            const float* __restrict__ wv, const float* __restrict__ wo,
            bf16_t* __restrict__ dst)
{
  const int z = blockIdx.z;
  const float* W = (z == 0) ? wq : (z == 1) ? wk : (z == 2) ? wv : wo;
  bf16_t* WT = dst + (size_t)z * Dm * Dm;
  __shared__ float tile[32][33];
  const int tx = threadIdx.x & 31, ty = threadIdx.x >> 5;
  const int nb = blockIdx.x * 32, kb = blockIdx.y * 32;
  #pragma unroll
  for (int p = 0; p < 4; ++p)
    tile[ty+8*p][tx] = W[(size_t)(kb+ty+8*p)*Dm + nb + tx];
  __syncthreads();
  #pragma unroll
  for (int p = 0; p < 4; ++p)
    WT[(size_t)(nb+ty+8*p)*Dm + kb + tx] = (bf16_t)tile[tx][ty+8*p];
}

// ------------- weight fp32 [K][N] -> bf16 transposed [N][K] -------------
__global__ __launch_bounds__(256)
void wconv_t(const float* __restrict__ W, bf16_t* __restrict__ WT, int K, int N)
{
  __shared__ float tile[32][33];
  const int tx = threadIdx.x & 31, ty = threadIdx.x >> 5;
  const int nb = blockIdx.x * 32, kb = blockIdx.y * 32;
  #pragma unroll
  for (int p = 0; p < 4; ++p)
    tile[ty+8*p][tx] = W[(size_t)(kb+ty+8*p)*N + nb + tx];
  __syncthreads();
  #pragma unroll
  for (int p = 0; p < 4; ++p)
    WT[(size_t)(nb+ty+8*p)*K + kb + tx] = (bf16_t)tile[tx][ty+8*p];
}

__global__ void bias_concat(const float* __restrict__ bq, const float* __restrict__ bk,
                            const float* __restrict__ bv, float* __restrict__ o)
{
  int i = blockIdx.x*256 + threadIdx.x;
  o[i] = bq[i]; o[Dm+i] = bk[i]; o[2*Dm+i] = bv[i];
}

// ----- V slice of qkv [B*S][6144] -> vT [B*H][128][2048] (bf16) -----
__global__ __launch_bounds__(256)
void vtrans(const bf16_t* __restrict__ qkv, bf16_t* __restrict__ vT)
{
  __shared__ bf16_t tile[32][33];
  const int tx = threadIdx.x & 31, ty = threadIdx.x >> 5;
  const int s0 = blockIdx.x*32, d0 = blockIdx.y*32, bh = blockIdx.z;
  const int b = bh >> 4, h = bh & 15;
  const bf16_t* src = qkv + (size_t)(b*SEQ)*QW + 2*Dm + h*HDm;
  #pragma unroll
  for (int p = 0; p < 4; ++p)
    tile[ty+8*p][tx] = src[(size_t)(s0+ty+8*p)*QW + d0 + tx];
  __syncthreads();
  bf16_t* dst = vT + (size_t)bh*HDm*SEQ;
  #pragma unroll
  for (int p = 0; p < 4; ++p)
    dst[(size_t)(d0+ty+8*p)*SEQ + s0 + tx] = tile[tx][ty+8*p];
}

// ---- GEMM 256x256, 8-phase, 2 K-tiles(BK=64)/iter, 8 waves (2Mx4N) ----
// MODE: 0 bf16+bias | 1 bf16+bias+GELU | 3 f32 raw partial (split-K)
template<int MODE>
__global__ __launch_bounds__(512, 2)
void gemm8p(const bf16_t* __restrict__ A, const bf16_t* __restrict__ BT,
            const float* __restrict__ bias,
            void* __restrict__ Cout, void* __restrict__ Cout2,
            int Ndim, int Kslice, int Kstride, int gn)
{
  // 2D XCD chunking: 2x4 chunk grid; chunk = bid&7 (XCD-pinned)
  const int gm = (int)gridDim.x / gn;
  const int cm = gm >> 1, cn = gn >> 2;
  const int c = blockIdx.x & 7;
  const int idx = blockIdx.x >> 3;
  const int mi = idx / cn, ni = idx - mi*cn;
  const int m0 = ((c >> 2)*cm + mi) * 256;
  const int n0 = ((c & 3)*cn + ni) * 256;
  const int kOff = blockIdx.y * Kslice;
  const int tid = threadIdx.x;
  const int lane = tid & 63;
  const int w = tid >> 6;
  const int wr = w >> 2, wc = w & 3;              // 2 x 4 waves
  const int lr = lane & 15, kg = lane >> 4;

  // 8 regions of 8192 elems: buf0{r0:A-h0, r1:A-h1, r2:B-h0, r3:B-h1} buf1{r4..r7}
  __shared__ __attribute__((aligned(16))) bf16_t lds[65536];

  f32x4 acc[8][4] = {};

  // --- staging: 4 streams, incremental pointers (+64 elems per call) ---
  const int r1   = tid >> 3;
  const int blk1 = (tid & 7) ^ (r1 & 7);
  const size_t rowoff = (size_t)64 * Kstride;
  const bf16_t* pA0 = A  + (size_t)(m0 + r1)*Kstride       + kOff + blk1*8;
  const bf16_t* pA1 = A  + (size_t)(m0 + 128 + r1)*Kstride + kOff + blk1*8;
  const bf16_t* pB0 = BT + (size_t)(n0 + r1)*Kstride       + kOff + blk1*8;
  const bf16_t* pB1 = BT + (size_t)(n0 + 128 + r1)*Kstride + kOff + blk1*8;
  bf16_t* const d0 = lds + (size_t)tid*8;

#define STG(p, region) do { \
    gload_lds16((p), d0 + (size_t)(region)*8192); \
    gload_lds16((p) + rowoff, d0 + (size_t)(region)*8192 + 4096); \
    (p) += 64; } while (0)

  // read A-half mh: rows wr*64 + ml*16 + lr within region (buf*4 + mh)
  auto readA = [&](int buf, int mh, bf16x8* f) {
    #pragma unroll
    for (int ml = 0; ml < 4; ++ml)
      #pragma unroll
      for (int kk = 0; kk < 2; ++kk) {
        const bf16_t* base = lds + (buf*4 + mh)*8192;
        const int row = wr*64 + ml*16 + lr;
        f[ml*2+kk] = *(const bf16x8*)(base + row*64 + (((kk*4+kg) ^ (row&7))*8));
      }
  };
  // read B-half nh: rows wc*32 + nl*16 + lr within region (buf*4 + 2 + nh)
  auto readB = [&](int buf, int nh, bf16x8* f) {
    #pragma unroll
    for (int nl = 0; nl < 2; ++nl)
      #pragma unroll
      for (int kk = 0; kk < 2; ++kk) {
        const bf16_t* base = lds + (buf*4 + 2 + nh)*8192;
        const int row = wc*32 + nl*16 + lr;
        f[nl*2+kk] = *(const bf16x8*)(base + row*64 + (((kk*4+kg) ^ (row&7))*8));
      }
  };
  auto mfma16 = [&](int mh, int nh, const bf16x8* Af, const bf16x8* Bf) {
    __builtin_amdgcn_s_setprio(1);
    #pragma unroll
    for (int ml = 0; ml < 4; ++ml)
      #pragma unroll
      for (int nl = 0; nl < 2; ++nl)
        #pragma unroll
        for (int kk = 0; kk < 2; ++kk)
          acc[mh*4+ml][nh*2+nl] =
            __builtin_amdgcn_mfma_f32_16x16x32_bf16(Af[ml*2+kk], Bf[nl*2+kk],
                                                    acc[mh*4+ml][nh*2+nl], 0, 0, 0);
    __builtin_amdgcn_s_setprio(0);
  };

#define BAR() __builtin_amdgcn_s_barrier()
#define LGKM0() asm volatile("s_waitcnt lgkmcnt(0)")

  bf16x8 Af0[8], Af1[8], Bf0[4], Bf1[4];      // even K-tile set
  bf16x8 Af0b[8], Af1b[8], Bf0b[4], Bf1b[4];  // odd K-tile set

  // prologue: stage t0 (r0-r3) then t1 (r4-r7); vmcnt(8) -> t0 resident.
  STG(pA0, 0); STG(pA1, 1); STG(pB0, 2); STG(pB1, 3);
  STG(pA0, 4); STG(pA1, 5); STG(pB0, 6); STG(pB1, 7);
  asm volatile("s_waitcnt vmcnt(8)" ::: "memory");
  BAR();

  const int NITER = Kslice >> 7;     // iterations of 2 K-tiles
  for (int j = 0; j < NITER; ++j) {
    const bool s2 = (j + 1 < NITER);

    // P1: reads r0 (A-h0 t0) + r2 (B-h0 t0); no stage
    readA(0, 0, Af0); readB(0, 0, Bf0);
    BAR(); LGKM0(); mfma16(0, 0, Af0, Bf0); BAR();

    // P2: reads r3 (B-h1 t0); stage r0 <- A-h0(t0+2)   [r0 last read P1]
    readB(0, 1, Bf1);
    if (s2) STG(pA0, 0);
    BAR(); LGKM0(); mfma16(0, 1, Af0, Bf1); BAR();

    // P3: reads r1 (A-h1 t0); stage r2 <- B-h0(t0+2)   [r2 last read P1]
    readA(0, 1, Af1);
    if (s2) STG(pB0, 2);
    BAR(); LGKM0(); mfma16(1, 1, Af1, Bf1);
    if (s2) asm volatile("s_waitcnt vmcnt(4)" ::: "memory");
    else    asm volatile("s_waitcnt vmcnt(0)" ::: "memory");
    BAR();

    // P4: reads r4 (A-h0 t1); stage r1 <- A-h1(t0+2), r3 <- B-h1(t0+2)
    readA(1, 0, Af0b);
    if (s2) { STG(pA1, 1); STG(pB1, 3); }
    BAR(); LGKM0(); mfma16(1, 0, Af1, Bf0); BAR();

    // P5: reads r6 (B-h0 t1); no stage
    readB(1, 0, Bf0b);
    BAR(); LGKM0(); mfma16(0, 0, Af0b, Bf0b); BAR();

    // P6: reads r7 (B-h1 t1); stage r4 <- A-h0(t1+2), r6 <- B-h0(t1+2)
    readB(1, 1, Bf1b);
    if (s2) { STG(pA0, 4); STG(pB0, 6); }
    BAR(); LGKM0(); mfma16(0, 1, Af0b, Bf1b); BAR();

    // P7: reads r5 (A-h1 t1); stage r7 <- B-h1(t1+2)   [r7 last read P6]
    readA(1, 1, Af1b);
    if (s2) STG(pB1, 7);
    BAR(); LGKM0(); mfma16(1, 1, Af1b, Bf1b); BAR();

    // P8: stage r5 <- A-h1(t1+2)                       [r5 last read P7]
    if (s2) STG(pA1, 5);
    BAR(); mfma16(1, 0, Af1b, Bf0b);
    if (s2) asm volatile("s_waitcnt vmcnt(8)" ::: "memory");
    else    asm volatile("s_waitcnt vmcnt(0)" ::: "memory");
    BAR();
  }
#undef STG
#undef BAR
#undef LGKM0

  // ---- epilogue ----
  // row(MF) = (MF>>2)*128 + wr*64 + (MF&3)*16 + kg*4 + jj
  // col(NF) = (NF>>1)*128 + wc*32 + (NF&1)*16 + lr
  if constexpr (MODE == 0 || MODE == 1) {
    __syncthreads();
    #pragma unroll
    for (int NF = 0; NF < 4; ++NF) {
      const int col = (NF>>1)*128 + wc*32 + (NF&1)*16 + lr;
      const float bv = bias[n0 + col];
      #pragma unroll
      for (int MF = 0; MF < 8; ++MF) {
        #pragma unroll
        for (int jj = 0; jj < 4; ++jj) {
          float v = acc[MF][NF][jj] + bv;
          if constexpr (MODE == 1) v = 0.5f*v*(1.f + erff(v*0.70710678118f));
          const int row = (MF>>2)*128 + wr*64 + (MF&3)*16 + kg*4 + jj;
          const int adr = row*256 + (((col >> 3) ^ (row & 7)) << 3) + (col & 7);
          lds[adr] = (bf16_t)v;
        }
      }
    }
    __syncthreads();
    bf16_t* outp = (bf16_t*)Cout;
    #pragma unroll
    for (int i = 0; i < 16; ++i) {
      const int s = tid + i*512;
      const int row = s >> 5, ch = s & 31;
      uint4 vv = *(const uint4*)(lds + row*256 + ((ch ^ (row & 7)) << 3));
      *(uint4*)(outp + (size_t)(m0 + row)*Ndim + n0 + ch*8) = vv;
    }
  } else {
    float* pout = (float*)(blockIdx.y ? Cout2 : Cout);
    #pragma unroll
    for (int NF = 0; NF < 4; ++NF) {
      const int col = n0 + (NF>>1)*128 + wc*32 + (NF&1)*16 + lr;
      #pragma unroll
      for (int MF = 0; MF < 8; ++MF) {
        const int rbase = m0 + (MF>>2)*128 + wr*64 + (MF&3)*16 + kg*4;
        #pragma unroll
        for (int jj = 0; jj < 4; ++jj)
          pout[(size_t)(rbase + jj)*Ndim + col] = acc[MF][NF][jj];
      }
    }
  }
}

// ---- split-K reduce: out = p0 + p1 + bias + resid (f32, Ndim pow2) ----
__global__ __launch_bounds__(256)
void splitk_reduce(const float* __restrict__ p0, const float* __restrict__ p1,
                   const float* __restrict__ bias, const float* __restrict__ resid,
                   float* __restrict__ out, int Ndim)
{
  const size_t e = ((size_t)blockIdx.x*256 + threadIdx.x) * 4;
  float4 a = *(const float4*)(p0 + e);
  float4 b = *(const float4*)(p1 + e);
  float4 r = *(const float4*)(resid + e);
  float4 bv = *(const float4*)(bias + (int)(e & (size_t)(Ndim - 1)));
  float4 o;
  o.x = a.x + b.x + bv.x + r.x;
  o.y = a.y + b.y + bv.y + r.y;
  o.z = a.z + b.z + bv.z + r.z;
  o.w = a.w + b.w + bv.w + r.w;
  *(float4*)(out + e) = o;
}

// ---- causal flash attention v7: fused balanced pair + K/V double-buffer ----
// 256 blocks x 512 thr. Waves 0-3 own q-tile pr, waves 4-7 own 15-pr.
// stage(t+1 -> buf^1) issued BEFORE compute(t): loads fly under MFMAs.
// One barrier + own-wave vmcnt(0) per iter. LDS 96KB (1 block/CU).
__global__ __launch_bounds__(512)
void flash_attn7(const bf16_t* __restrict__ qkv, const bf16_t* __restrict__ vT,
                 bf16_t* __restrict__ ctx)
{
  const int bid = blockIdx.x;                  // 0..255
  const int bh  = (bid & 7) + 8 * ((bid >> 3) & 3);  // XCD-pinned head
  const int pr  = bid >> 5;                    // 0..7 pair index
  const int b = bh >> 4, h = bh & 15;
  const int tid = threadIdx.x;
  const int lane = tid & 63;
  const int w = tid >> 6;                      // 0..7
  const int wg = w >> 2;                       // 0: qi=pr, 1: qi=15-pr
  const int wsub = w & 3;
  const int lr = lane & 15, kg = lane >> 4;

  const int qi = wg ? (15 - pr) : pr;
  const int Q0 = qi * 128;
  const int q0w = Q0 + wsub * 32;

  __shared__ __attribute__((aligned(16))) bf16_t Ks[2][64*128];
  __shared__ __attribute__((aligned(16))) bf16_t Vs[2][128*64];
  __shared__ __attribute__((aligned(16))) bf16_t Plds[8*2048];

  const bf16_t* kbase = qkv + (size_t)(b*SEQ)*QW + Dm + h*HDm;
  const bf16_t* vbase = vT + (size_t)bh*HDm*SEQ;
  const float scl = 0.08838834764831845f * 1.44269504089f; // 1/sqrt(128)*log2(e)

  auto stage = [&](int buf, int k0) {
    #pragma unroll
    for (int i = 0; i < 2; ++i) {
      const int s = tid + i*512;                 // K slot (1024 total)
      const int row = s >> 4, sl = s & 15;
      gload_lds16(kbase + (size_t)(k0 + row)*QW + (sl ^ (row & 7))*8, Ks[buf] + s*8);
    }
    #pragma unroll
    for (int i = 0; i < 2; ++i) {
      const int s = tid + i*512;                 // V slot (1024 total)
      const int row = s >> 3, sl = s & 7;
      gload_lds16(vbase + (size_t)row*SEQ + k0 + (sl ^ (row & 7))*8, Vs[buf] + s*8);
    }
  };

  bf16x8 qf[2][4];
  #pragma unroll
  for (int rt = 0; rt < 2; ++rt) {
    const bf16_t* qb = qkv + (size_t)(b*SEQ + q0w + rt*16 + lr)*QW + h*HDm;
    #pragma unroll
    for (int g = 0; g < 4; ++g)
      qf[rt][g] = *(const bf16x8*)(qb + g*32 + kg*8);
  }

  float mrow[2][4], lsum[2][4];
  f32x4 oacc[2][8];
  #pragma unroll
  for (int rt = 0; rt < 2; ++rt) {
    #pragma unroll
    for (int j = 0; j < 4; ++j) { mrow[rt][j] = -INFINITY; lsum[rt][j] = 0.f; }
    #pragma unroll
    for (int dt = 0; dt < 8; ++dt) oacc[rt][dt] = (f32x4){0.f,0.f,0.f,0.f};
  }

  const int NT = (16 - pr) * 2;                // union k-range of the pair
  stage(0, 0);
  asm volatile("s_waitcnt vmcnt(0)" ::: "memory");
  __syncthreads();
  for (int t = 0; t < NT; ++t) {
    const int k0 = t * 64;
    const int buf = t & 1;
    const bool more = (t + 1 < NT);
    // issue next tile's stage into the other buffer; flies under compute
    if (more) stage(buf ^ 1, k0 + 64);
    if (k0 < q0w + 32) {
      f32x4 sa[2][4];
      #pragma unroll
      for (int rt = 0; rt < 2; ++rt)
        #pragma unroll
        for (int ct = 0; ct < 4; ++ct) sa[rt][ct] = (f32x4){0.f,0.f,0.f,0.f};
      #pragma unroll
      for (int ct = 0; ct < 4; ++ct) {
        const int krow = ct*16 + lr;
        #pragma unroll
        for (int g = 0; g < 4; ++g) {
          bf16x8 kf = *(const bf16x8*)(Ks[buf] + krow*128 + ((4*g + kg) ^ (krow & 7))*8);
          sa[0][ct] = __builtin_amdgcn_mfma_f32_16x16x32_bf16(qf[0][g], kf, sa[0][ct], 0, 0, 0);
          sa[1][ct] = __builtin_amdgcn_mfma_f32_16x16x32_bf16(qf[1][g], kf, sa[1][ct], 0, 0, 0);
        }
      }
      #pragma unroll
      for (int rt = 0; rt < 2; ++rt)
        #pragma unroll
        for (int ct = 0; ct < 4; ++ct)
          #pragma unroll
          for (int j = 0; j < 4; ++j) sa[rt][ct][j] *= scl;
      if (k0 + 63 > q0w) {
        #pragma unroll
        for (int ct = 0; ct < 4; ++ct) {
          const int kidx = k0 + ct*16 + lr;
          #pragma unroll
          for (int rt = 0; rt < 2; ++rt)
            #pragma unroll
            for (int j = 0; j < 4; ++j) {
              const int qidx = q0w + rt*16 + kg*4 + j;
              if (kidx > qidx) sa[rt][ct][j] = -INFINITY;
            }
        }
      }
      #pragma unroll
      for (int rt = 0; rt < 2; ++rt) {
        #pragma unroll
        for (int j = 0; j < 4; ++j) {
          const int prow = kg*4 + j;
          float x0 = sa[rt][0][j], x1 = sa[rt][1][j], x2 = sa[rt][2][j], x3 = sa[rt][3][j];
          float v = fmaxf(fmaxf(x0, x1), fmaxf(x2, x3));
          v = fmaxf(v, __shfl_xor(v, 1));
          v = fmaxf(v, __shfl_xor(v, 2));
          v = fmaxf(v, __shfl_xor(v, 4));
          v = fmaxf(v, __shfl_xor(v, 8));
          const float mn = fmaxf(mrow[rt][j], v);
          const float alpha = exp2f(mrow[rt][j] - mn);
          mrow[rt][j] = mn;
          float p0 = exp2f(x0 - mn), p1 = exp2f(x1 - mn);
          float p2 = exp2f(x2 - mn), p3 = exp2f(x3 - mn);
          float ss = (p0 + p1) + (p2 + p3);
          ss += __shfl_xor(ss, 1);
          ss += __shfl_xor(ss, 2);
          ss += __shfl_xor(ss, 4);
          ss += __shfl_xor(ss, 8);
          lsum[rt][j] = lsum[rt][j]*alpha + ss;
          #pragma unroll
          for (int dt = 0; dt < 8; ++dt) oacc[rt][dt][j] *= alpha;
          const int base = w*2048 + rt*1024 + prow*64;
          const int sw = (prow & 7) << 3;
          Plds[(base + ( 0 + lr)) ^ sw] = (bf16_t)p0;
          Plds[(base + (16 + lr)) ^ sw] = (bf16_t)p1;
          Plds[(base + (32 + lr)) ^ sw] = (bf16_t)p2;
          Plds[(base + (48 + lr)) ^ sw] = (bf16_t)p3;
        }
      }
      // Plds region is per-wave private: same-wave write->read ordered by lgkm
      bf16x8 pf[2][2];
      {
        const int sw = (lr & 7) << 3;
        #pragma unroll
        for (int rt = 0; rt < 2; ++rt) {
          pf[rt][0] = *(const bf16x8*)(Plds + ((w*2048 + rt*1024 + lr*64 +      kg*8) ^ sw));
          pf[rt][1] = *(const bf16x8*)(Plds + ((w*2048 + rt*1024 + lr*64 + 32 + kg*8) ^ sw));
        }
      }
      #pragma unroll
      for (int dt = 0; dt < 8; ++dt) {
        const int vrow = dt*16 + lr;
        #pragma unroll
        for (int kc = 0; kc < 2; ++kc) {
          bf16x8 vf = *(const bf16x8*)(Vs[buf] + vrow*64 + ((4*kc + kg) ^ (vrow & 7))*8);
          oacc[0][dt] = __builtin_amdgcn_mfma_f32_16x16x32_bf16(pf[0][kc], vf, oacc[0][dt], 0, 0, 0);
          oacc[1][dt] = __builtin_amdgcn_mfma_f32_16x16x32_bf16(pf[1][kc], vf, oacc[1][dt], 0, 0, 0);
        }
      }
    }
    // drain this wave's stage loads (issued at iter top), then block barrier:
    // orders (a) next buf resident for all waves, (b) all reads of current
    // buf complete before it is restaged next iter.
    if (more) asm volatile("s_waitcnt vmcnt(0)" ::: "memory");
    __syncthreads();
  }

  #pragma unroll
  for (int rt = 0; rt < 2; ++rt) {
    bf16_t* cb = ctx + (size_t)(b*SEQ + q0w + rt*16 + kg*4)*Dm + h*HDm;
    #pragma unroll
    for (int j = 0; j < 4; ++j) {
      const float inv = 1.f / lsum[rt][j];
      #pragma unroll
      for (int dt = 0; dt < 8; ++dt)
        cb[(size_t)j*Dm + dt*16 + lr] = (bf16_t)(oacc[rt][dt][j] * inv);
    }
  }
}

} // namespace

extern "C" void kernel_launch(void* const* d_in, const int* in_sizes, int n_in,
                              void* d_out, int out_size, void* d_ws, size_t ws_size,
                              hipStream_t stream)
{
  const float* x   = (const float*)d_in[0];
  const float* g1  = (const float*)d_in[1];
  const float* s1  = (const float*)d_in[2];
  const float* wq  = (const float*)d_in[3];
  const float* bq  = (const float*)d_in[4];
  const float* wk  = (const float*)d_in[5];
  const float* bk  = (const float*)d_in[6];
  const float* wv  = (const float*)d_in[7];
  const float* bv  = (const float*)d_in[8];
  const float* wo  = (const float*)d_in[9];
  const float* bo  = (const float*)d_in[10];
  const float* g2  = (const float*)d_in[11];
  const float* s2  = (const float*)d_in[12];
  const float* w1  = (const float*)d_in[13];
  const float* b1  = (const float*)d_in[14];
  const float* w2  = (const float*)d_in[15];
  const float* b2  = (const float*)d_in[16];
  float* out = (float*)d_out;

  char* p = (char*)d_ws;
  bf16_t* wqkvT = (bf16_t*)p;  p += (size_t)QW*Dm*2;     // + woT right after
  bf16_t* woT   = (bf16_t*)p;  p += (size_t)Dm*Dm*2;
  bf16_t* w1T   = (bf16_t*)p;  p += (size_t)FFm*Dm*2;
  bf16_t* w2T   = (bf16_t*)p;  p += (size_t)Dm*FFm*2;
  float*  bqkv  = (float*)p;   p += (size_t)QW*4;
  bf16_t* hbuf  = (bf16_t*)p;  p += (size_t)MR*Dm*2;
  bf16_t* qkv   = (bf16_t*)p;  p += (size_t)MR*QW*2;
  bf16_t* vTb   = (bf16_t*)p;  p += (size_t)32*HDm*SEQ*2;
  bf16_t* ctx   = (bf16_t*)p;  p += (size_t)MR*Dm*2;
  float*  x1    = (float*)p;   p += (size_t)MR*Dm*4;
  bf16_t* ffn1  = qkv;                  // FFN1 out: spans qkv+vTb (67.1 MB)
  float*  prj0  = (float*)qkv;
  float*  prj1  = (float*)qkv + (size_t)MR*Dm;
  float*  f2p0  = (float*)w1T;
  float*  f2p1  = (float*)wqkvT;

  wconv4<<<dim3(Dm/32, Dm/32, 4), 256, 0, stream>>>(wq, wk, wv, wo, wqkvT);
  wconv_t<<<dim3(FFm/32, Dm/32), 256, 0, stream>>>(w1, w1T, Dm, FFm);
  wconv_t<<<dim3(Dm/32, FFm/32), 256, 0, stream>>>(w2, w2T, FFm, Dm);
  bias_concat<<<dim3(Dm/256), 256, 0, stream>>>(bq, bk, bv, bqkv);

  ln_kernel<<<dim3(MR), 256, 0, stream>>>(x, g1, s1, hbuf);
  gemm8p<0><<<dim3((QW/256)*(MR/256), 1), 512, 0, stream>>>(
      hbuf, wqkvT, bqkv, qkv, nullptr, QW, Dm, Dm, QW/256);
  vtrans<<<dim3(SEQ/32, HDm/32, 32), 256, 0, stream>>>(qkv, vTb);
  flash_attn7<<<dim3(256), 512, 0, stream>>>(qkv, vTb, ctx);
  gemm8p<3><<<dim3((Dm/256)*(MR/256), 2), 512, 0, stream>>>(
      ctx, woT, nullptr, prj0, prj1, Dm, Dm/2, Dm, Dm/256);
  // fused: x1 = prj0+prj1+bo+x ; hbuf = LN2(x1)
  ln_fused<<<dim3(MR), 256, 0, stream>>>(prj0, prj1, bo, x, g2, s2, x1, hbuf);
  gemm8p<1><<<dim3((FFm/256)*(MR/256), 1), 512, 0, stream>>>(
      hbuf, w1T, b1, ffn1, nullptr, FFm, Dm, Dm, FFm/256);
  gemm8p<3><<<dim3((Dm/256)*(MR/256), 2), 512, 0, stream>>>(
      ffn1, w2T, nullptr, f2p0, f2p1, Dm, FFm/2, FFm, Dm/256);
  splitk_reduce<<<dim3(MR*Dm/1024), 256, 0, stream>>>(f2p0, f2p1, b2, x1, out, Dm);
}

// Round 19
// 646.789 us; speedup vs baseline: 1.0931x; 1.0198x over previous
//
#include <hip/hip_runtime.h>
#include <hip/hip_bf16.h>
#include <math.h>

namespace {

constexpr int Dm  = 2048;
constexpr int FFm = 8192;
constexpr int SEQ = 2048;
constexpr int HDm = 128;
constexpr int MR  = 4096;     // B*S
constexpr int QW  = 3 * Dm;   // 6144

typedef __bf16 bf16_t;
typedef __bf16 bf16x8 __attribute__((ext_vector_type(8)));
typedef float  f32x4  __attribute__((ext_vector_type(4)));

typedef __attribute__((address_space(1))) const void as1_void;
typedef __attribute__((address_space(3))) void as3_void;

__device__ __forceinline__ void gload_lds16(const void* g, void* l) {
  __builtin_amdgcn_global_load_lds((as1_void*)g, (as3_void*)l, 16, 0, 0);
}

// ---------------- LayerNorm: fp32 in -> bf16 out ----------------
__global__ __launch_bounds__(256)
void ln_kernel(const float* __restrict__ x, const float* __restrict__ sc,
               const float* __restrict__ sh, bf16_t* __restrict__ out)
{
  const int row = blockIdx.x;
  const int tid = threadIdx.x;
  const float4* xr = (const float4*)(x + (size_t)row * Dm);
  float4 v0 = xr[tid*2], v1 = xr[tid*2+1];
  float s  = v0.x+v0.y+v0.z+v0.w + v1.x+v1.y+v1.z+v1.w;
  float s2 = v0.x*v0.x+v0.y*v0.y+v0.z*v0.z+v0.w*v0.w
           + v1.x*v1.x+v1.y*v1.y+v1.z*v1.z+v1.w*v1.w;
  #pragma unroll
  for (int off = 32; off; off >>= 1) { s += __shfl_xor(s, off); s2 += __shfl_xor(s2, off); }
  __shared__ float red[8];
  if ((tid & 63) == 0) { red[(tid>>6)*2] = s; red[(tid>>6)*2+1] = s2; }
  __syncthreads();
  s  = red[0]+red[2]+red[4]+red[6];
  s2 = red[1]+red[3]+red[5]+red[7];
  const float mean = s * (1.f/Dm);
  const float var  = fmaxf(s2 * (1.f/Dm) - mean*mean, 0.f);
  const float rstd = rsqrtf(var + 1e-5f);
  const float4* scp = (const float4*)sc;
  const float4* shp = (const float4*)sh;
  float4 sc0 = scp[tid*2], sc1 = scp[tid*2+1];
  float4 sh0 = shp[tid*2], sh1 = shp[tid*2+1];
  __attribute__((aligned(16))) bf16_t ob[8];
  ob[0] = (bf16_t)((v0.x-mean)*rstd*sc0.x + sh0.x);
  ob[1] = (bf16_t)((v0.y-mean)*rstd*sc0.y + sh0.y);
  ob[2] = (bf16_t)((v0.z-mean)*rstd*sc0.z + sh0.z);
  ob[3] = (bf16_t)((v0.w-mean)*rstd*sc0.w + sh0.w);
  ob[4] = (bf16_t)((v1.x-mean)*rstd*sc1.x + sh1.x);
  ob[5] = (bf16_t)((v1.y-mean)*rstd*sc1.y + sh1.y);
  ob[6] = (bf16_t)((v1.z-mean)*rstd*sc1.z + sh1.z);
  ob[7] = (bf16_t)((v1.w-mean)*rstd*sc1.w + sh1.w);
  *(uint4*)(out + (size_t)row*Dm + tid*8) = *(const uint4*)ob;
}

// -- fused: v = p0+p1+bias+resid; x1 = v (f32); out = LN(v) (bf16) --
__global__ __launch_bounds__(256)
void ln_fused(const float* __restrict__ p0, const float* __restrict__ p1,
              const float* __restrict__ bias, const float* __restrict__ resid,
              const float* __restrict__ sc, const float* __restrict__ sh,
              float* __restrict__ x1, bf16_t* __restrict__ out)
{
  const int row = blockIdx.x;
  const int tid = threadIdx.x;
  const size_t base = (size_t)row * Dm + tid*8;
  float v[8];
  #pragma unroll
  for (int hh = 0; hh < 2; ++hh) {
    float4 a  = *(const float4*)(p0 + base + hh*4);
    float4 b  = *(const float4*)(p1 + base + hh*4);
    float4 r  = *(const float4*)(resid + base + hh*4);
    float4 bv = *(const float4*)(bias + tid*8 + hh*4);
    v[hh*4+0] = a.x + b.x + bv.x + r.x;
    v[hh*4+1] = a.y + b.y + bv.y + r.y;
    v[hh*4+2] = a.z + b.z + bv.z + r.z;
    v[hh*4+3] = a.w + b.w + bv.w + r.w;
  }
  *(float4*)(x1 + base)     = *(const float4*)&v[0];
  *(float4*)(x1 + base + 4) = *(const float4*)&v[4];
  float s = 0.f, s2 = 0.f;
  #pragma unroll
  for (int j = 0; j < 8; ++j) { s += v[j]; s2 += v[j]*v[j]; }
  #pragma unroll
  for (int off = 32; off; off >>= 1) { s += __shfl_xor(s, off); s2 += __shfl_xor(s2, off); }
  __shared__ float red[8];
  if ((tid & 63) == 0) { red[(tid>>6)*2] = s; red[(tid>>6)*2+1] = s2; }
  __syncthreads();
  s  = red[0]+red[2]+red[4]+red[6];
  s2 = red[1]+red[3]+red[5]+red[7];
  const float mean = s * (1.f/Dm);
  const float var  = fmaxf(s2 * (1.f/Dm) - mean*mean, 0.f);
  const float rstd = rsqrtf(var + 1e-5f);
  __attribute__((aligned(16))) bf16_t ob[8];
  #pragma unroll
  for (int hh = 0; hh < 2; ++hh) {
    float4 scv = *(const float4*)(sc + tid*8 + hh*4);
    float4 shv = *(const float4*)(sh + tid*8 + hh*4);
    ob[hh*4+0] = (bf16_t)((v[hh*4+0]-mean)*rstd*scv.x + shv.x);
    ob[hh*4+1] = (bf16_t)((v[hh*4+1]-mean)*rstd*scv.y + shv.y);
    ob[hh*4+2] = (bf16_t)((v[hh*4+2]-mean)*rstd*scv.z + shv.z);
    ob[hh*4+3] = (bf16_t)((v[hh*4+3]-mean)*rstd*scv.w + shv.w);
  }
  *(uint4*)(out + base) = *(const uint4*)ob;
}

// ----- weights q,k,v,o (each [Dm][Dm] fp32) -> bf16 transposed, packed -----
__global__ __launch_bounds__(256)
void wconv4(const float* __restrict__ wq, const float* __restrict__ wk,
            const float* __restrict__ wv, const float* __restrict__ wo,
            bf16_t* __restrict__ dst)
{
  const int z = blockIdx.z;
  const float* W = (z == 0) ? wq : (z == 1) ? wk : (z == 2) ? wv : wo;
  bf16_t* WT = dst + (size_t)z * Dm * Dm;
  __shared__ float tile[32][33];
  const int tx = threadIdx.x & 31, ty = threadIdx.x >> 5;
  const int nb = blockIdx.x * 32, kb = blockIdx.y * 32;
  #pragma unroll
  for (int p = 0; p < 4; ++p)
    tile[ty+8*p][tx] = W[(size_t)(kb+ty+8*p)*Dm + nb + tx];
  __syncthreads();
  #pragma unroll
  for (int p = 0; p < 4; ++p)
    WT[(size_t)(nb+ty+8*p)*Dm + kb + tx] = (bf16_t)tile[tx][ty+8*p];
}

// ------------- weight fp32 [K][N] -> bf16 transposed [N][K] -------------
__global__ __launch_bounds__(256)
void wconv_t(const float* __restrict__ W, bf16_t* __restrict__ WT, int K, int N)
{
  __shared__ float tile[32][33];
  const int tx = threadIdx.x & 31, ty = threadIdx.x >> 5;
  const int nb = blockIdx.x * 32, kb = blockIdx.y * 32;
  #pragma unroll
  for (int p = 0; p < 4; ++p)
    tile[ty+8*p][tx] = W[(size_t)(kb+ty+8*p)*N + nb + tx];
  __syncthreads();
  #pragma unroll
  for (int p = 0; p < 4; ++p)
    WT[(size_t)(nb+ty+8*p)*K + kb + tx] = (bf16_t)tile[tx][ty+8*p];
}

__global__ void bias_concat(const float* __restrict__ bq, const float* __restrict__ bk,
                            const float* __restrict__ bv, float* __restrict__ o)
{
  int i = blockIdx.x*256 + threadIdx.x;
  o[i] = bq[i]; o[Dm+i] = bk[i]; o[2*Dm+i] = bv[i];
}

// ----- V partials [B*S][2048] (bf16 x2) + bias -> vT [B*H][128][2048] -----
__global__ __launch_bounds__(256)
void vtrans_fused(const bf16_t* __restrict__ vp0, const bf16_t* __restrict__ vp1,
                  const float* __restrict__ bv, bf16_t* __restrict__ vT)
{
  __shared__ bf16_t tile[32][33];
  const int tx = threadIdx.x & 31, ty = threadIdx.x >> 5;
  const int s0 = blockIdx.x*32, d0 = blockIdx.y*32, bh = blockIdx.z;
  const int b = bh >> 4, h = bh & 15;
  const int gd = h*HDm + d0 + tx;                 // global V column
  const float bias = bv[gd];
  #pragma unroll
  for (int p = 0; p < 4; ++p) {
    const size_t idx = (size_t)(b*SEQ + s0 + ty + 8*p)*Dm + gd;
    tile[ty+8*p][tx] = (bf16_t)((float)vp0[idx] + (float)vp1[idx] + bias);
  }
  __syncthreads();
  bf16_t* dst = vT + (size_t)bh*HDm*SEQ;
  #pragma unroll
  for (int p = 0; p < 4; ++p)
    dst[(size_t)(d0+ty+8*p)*SEQ + s0 + tx] = tile[tx][ty+8*p];
}

// ---- GEMM 256x256, 8-phase, 2 K-tiles(BK=64)/iter, 8 waves (2Mx4N) ----
// MODE: 0 bf16+bias | 1 bf16+bias+GELU | 3 f32 raw partial | 4 bf16 raw partial
template<int MODE>
__global__ __launch_bounds__(512, 2)
void gemm8p(const bf16_t* __restrict__ A, const bf16_t* __restrict__ BT,
            const float* __restrict__ bias,
            void* __restrict__ Cout, void* __restrict__ Cout2,
            int Ndim, int Kslice, int Kstride, int gn)
{
  // 2D XCD chunking: 2x4 chunk grid; chunk = bid&7 (XCD-pinned)
  const int gm = (int)gridDim.x / gn;
  const int cm = gm >> 1, cn = gn >> 2;
  const int c = blockIdx.x & 7;
  const int idx = blockIdx.x >> 3;
  const int mi = idx / cn, ni = idx - mi*cn;
  const int m0 = ((c >> 2)*cm + mi) * 256;
  const int n0 = ((c & 3)*cn + ni) * 256;
  const int kOff = blockIdx.y * Kslice;
  const int tid = threadIdx.x;
  const int lane = tid & 63;
  const int w = tid >> 6;
  const int wr = w >> 2, wc = w & 3;              // 2 x 4 waves
  const int lr = lane & 15, kg = lane >> 4;

  // 8 regions of 8192 elems: buf0{r0:A-h0, r1:A-h1, r2:B-h0, r3:B-h1} buf1{r4..r7}
  __shared__ __attribute__((aligned(16))) bf16_t lds[65536];

  f32x4 acc[8][4] = {};

  // --- staging: 4 streams, incremental pointers (+64 elems per call) ---
  const int r1   = tid >> 3;
  const int blk1 = (tid & 7) ^ (r1 & 7);
  const size_t rowoff = (size_t)64 * Kstride;
  const bf16_t* pA0 = A  + (size_t)(m0 + r1)*Kstride       + kOff + blk1*8;
  const bf16_t* pA1 = A  + (size_t)(m0 + 128 + r1)*Kstride + kOff + blk1*8;
  const bf16_t* pB0 = BT + (size_t)(n0 + r1)*Kstride       + kOff + blk1*8;
  const bf16_t* pB1 = BT + (size_t)(n0 + 128 + r1)*Kstride + kOff + blk1*8;
  bf16_t* const d0 = lds + (size_t)tid*8;

#define STG(p, region) do { \
    gload_lds16((p), d0 + (size_t)(region)*8192); \
    gload_lds16((p) + rowoff, d0 + (size_t)(region)*8192 + 4096); \
    (p) += 64; } while (0)

  // read A-half mh: rows wr*64 + ml*16 + lr within region (buf*4 + mh)
  auto readA = [&](int buf, int mh, bf16x8* f) {
    #pragma unroll
    for (int ml = 0; ml < 4; ++ml)
      #pragma unroll
      for (int kk = 0; kk < 2; ++kk) {
        const bf16_t* base = lds + (buf*4 + mh)*8192;
        const int row = wr*64 + ml*16 + lr;
        f[ml*2+kk] = *(const bf16x8*)(base + row*64 + (((kk*4+kg) ^ (row&7))*8));
      }
  };
  // read B-half nh: rows wc*32 + nl*16 + lr within region (buf*4 + 2 + nh)
  auto readB = [&](int buf, int nh, bf16x8* f) {
    #pragma unroll
    for (int nl = 0; nl < 2; ++nl)
      #pragma unroll
      for (int kk = 0; kk < 2; ++kk) {
        const bf16_t* base = lds + (buf*4 + 2 + nh)*8192;
        const int row = wc*32 + nl*16 + lr;
        f[nl*2+kk] = *(const bf16x8*)(base + row*64 + (((kk*4+kg) ^ (row&7))*8));
      }
  };
  auto mfma16 = [&](int mh, int nh, const bf16x8* Af, const bf16x8* Bf) {
    __builtin_amdgcn_s_setprio(1);
    #pragma unroll
    for (int ml = 0; ml < 4; ++ml)
      #pragma unroll
      for (int nl = 0; nl < 2; ++nl)
        #pragma unroll
        for (int kk = 0; kk < 2; ++kk)
          acc[mh*4+ml][nh*2+nl] =
            __builtin_amdgcn_mfma_f32_16x16x32_bf16(Af[ml*2+kk], Bf[nl*2+kk],
                                                    acc[mh*4+ml][nh*2+nl], 0, 0, 0);
    __builtin_amdgcn_s_setprio(0);
  };

#define BAR() __builtin_amdgcn_s_barrier()
#define LGKM0() asm volatile("s_waitcnt lgkmcnt(0)")

  bf16x8 Af0[8], Af1[8], Bf0[4], Bf1[4];      // even K-tile set
  bf16x8 Af0b[8], Af1b[8], Bf0b[4], Bf1b[4];  // odd K-tile set

  // prologue: stage t0 (r0-r3) then t1 (r4-r7); vmcnt(8) -> t0 resident.
  STG(pA0, 0); STG(pA1, 1); STG(pB0, 2); STG(pB1, 3);
  STG(pA0, 4); STG(pA1, 5); STG(pB0, 6); STG(pB1, 7);
  asm volatile("s_waitcnt vmcnt(8)" ::: "memory");
  BAR();

  const int NITER = Kslice >> 7;     // iterations of 2 K-tiles
  for (int j = 0; j < NITER; ++j) {
    const bool s2 = (j + 1 < NITER);

    // P1: reads r0 (A-h0 t0) + r2 (B-h0 t0); no stage
    readA(0, 0, Af0); readB(0, 0, Bf0);
    BAR(); LGKM0(); mfma16(0, 0, Af0, Bf0); BAR();

    // P2: reads r3 (B-h1 t0); stage r0 <- A-h0(t0+2)   [r0 last read P1]
    readB(0, 1, Bf1);
    if (s2) STG(pA0, 0);
    BAR(); LGKM0(); mfma16(0, 1, Af0, Bf1); BAR();

    // P3: reads r1 (A-h1 t0); stage r2 <- B-h0(t0+2)   [r2 last read P1]
    readA(0, 1, Af1);
    if (s2) STG(pB0, 2);
    BAR(); LGKM0(); mfma16(1, 1, Af1, Bf1);
    if (s2) asm volatile("s_waitcnt vmcnt(4)" ::: "memory");
    else    asm volatile("s_waitcnt vmcnt(0)" ::: "memory");
    BAR();

    // P4: reads r4 (A-h0 t1); stage r1 <- A-h1(t0+2), r3 <- B-h1(t0+2)
    readA(1, 0, Af0b);
    if (s2) { STG(pA1, 1); STG(pB1, 3); }
    BAR(); LGKM0(); mfma16(1, 0, Af1, Bf0); BAR();

    // P5: reads r6 (B-h0 t1); no stage
    readB(1, 0, Bf0b);
    BAR(); LGKM0(); mfma16(0, 0, Af0b, Bf0b); BAR();

    // P6: reads r7 (B-h1 t1); stage r4 <- A-h0(t1+2), r6 <- B-h0(t1+2)
    readB(1, 1, Bf1b);
    if (s2) { STG(pA0, 4); STG(pB0, 6); }
    BAR(); LGKM0(); mfma16(0, 1, Af0b, Bf1b); BAR();

    // P7: reads r5 (A-h1 t1); stage r7 <- B-h1(t1+2)   [r7 last read P6]
    readA(1, 1, Af1b);
    if (s2) STG(pB1, 7);
    BAR(); LGKM0(); mfma16(1, 1, Af1b, Bf1b); BAR();

    // P8: stage r5 <- A-h1(t1+2)                       [r5 last read P7]
    if (s2) STG(pA1, 5);
    BAR(); mfma16(1, 0, Af1b, Bf0b);
    if (s2) asm volatile("s_waitcnt vmcnt(8)" ::: "memory");
    else    asm volatile("s_waitcnt vmcnt(0)" ::: "memory");
    BAR();
  }
#undef STG
#undef BAR
#undef LGKM0

  // ---- epilogue ----
  // row(MF) = (MF>>2)*128 + wr*64 + (MF&3)*16 + kg*4 + jj
  // col(NF) = (NF>>1)*128 + wc*32 + (NF&1)*16 + lr
  if constexpr (MODE == 0 || MODE == 1 || MODE == 4) {
    __syncthreads();
    #pragma unroll
    for (int NF = 0; NF < 4; ++NF) {
      const int col = (NF>>1)*128 + wc*32 + (NF&1)*16 + lr;
      float bv = 0.f;
      if constexpr (MODE != 4) bv = bias[n0 + col];
      #pragma unroll
      for (int MF = 0; MF < 8; ++MF) {
        #pragma unroll
        for (int jj = 0; jj < 4; ++jj) {
          float v = acc[MF][NF][jj] + bv;
          if constexpr (MODE == 1) v = 0.5f*v*(1.f + erff(v*0.70710678118f));
          const int row = (MF>>2)*128 + wr*64 + (MF&3)*16 + kg*4 + jj;
          const int adr = row*256 + (((col >> 3) ^ (row & 7)) << 3) + (col & 7);
          lds[adr] = (bf16_t)v;
        }
      }
    }
    __syncthreads();
    bf16_t* outp;
    if constexpr (MODE == 4) outp = (bf16_t*)(blockIdx.y ? Cout2 : Cout);
    else                     outp = (bf16_t*)Cout;
    #pragma unroll
    for (int i = 0; i < 16; ++i) {
      const int s = tid + i*512;
      const int row = s >> 5, ch = s & 31;
      uint4 vv = *(const uint4*)(lds + row*256 + ((ch ^ (row & 7)) << 3));
      *(uint4*)(outp + (size_t)(m0 + row)*Ndim + n0 + ch*8) = vv;
    }
  } else {
    float* pout = (float*)(blockIdx.y ? Cout2 : Cout);
    #pragma unroll
    for (int NF = 0; NF < 4; ++NF) {
      const int col = n0 + (NF>>1)*128 + wc*32 + (NF&1)*16 + lr;
      #pragma unroll
      for (int MF = 0; MF < 8; ++MF) {
        const int rbase = m0 + (MF>>2)*128 + wr*64 + (MF&3)*16 + kg*4;
        #pragma unroll
        for (int jj = 0; jj < 4; ++jj)
          pout[(size_t)(rbase + jj)*Ndim + col] = acc[MF][NF][jj];
      }
    }
  }
}

// ---- split-K reduce: out = p0 + p1 + bias + resid (f32, Ndim pow2) ----
__global__ __launch_bounds__(256)
void splitk_reduce(const float* __restrict__ p0, const float* __restrict__ p1,
                   const float* __restrict__ bias, const float* __restrict__ resid,
                   float* __restrict__ out, int Ndim)
{
  const size_t e = ((size_t)blockIdx.x*256 + threadIdx.x) * 4;
  float4 a = *(const float4*)(p0 + e);
  float4 b = *(const float4*)(p1 + e);
  float4 r = *(const float4*)(resid + e);
  float4 bv = *(const float4*)(bias + (int)(e & (size_t)(Ndim - 1)));
  float4 o;
  o.x = a.x + b.x + bv.x + r.x;
  o.y = a.y + b.y + bv.y + r.y;
  o.z = a.z + b.z + bv.z + r.z;
  o.w = a.w + b.w + bv.w + r.w;
  *(float4*)(out + e) = o;
}

// ---- causal flash attention v7: fused balanced pair + K/V double-buffer ----
__global__ __launch_bounds__(512)
void flash_attn7(const bf16_t* __restrict__ qkv, const bf16_t* __restrict__ vT,
                 bf16_t* __restrict__ ctx)
{
  const int bid = blockIdx.x;                  // 0..255
  const int bh  = (bid & 7) + 8 * ((bid >> 3) & 3);  // XCD-pinned head
  const int pr  = bid >> 5;                    // 0..7 pair index
  const int b = bh >> 4, h = bh & 15;
  const int tid = threadIdx.x;
  const int lane = tid & 63;
  const int w = tid >> 6;                      // 0..7
  const int wg = w >> 2;                       // 0: qi=pr, 1: qi=15-pr
  const int wsub = w & 3;
  const int lr = lane & 15, kg = lane >> 4;

  const int qi = wg ? (15 - pr) : pr;
  const int Q0 = qi * 128;
  const int q0w = Q0 + wsub * 32;

  __shared__ __attribute__((aligned(16))) bf16_t Ks[2][64*128];
  __shared__ __attribute__((aligned(16))) bf16_t Vs[2][128*64];
  __shared__ __attribute__((aligned(16))) bf16_t Plds[8*2048];

  const bf16_t* kbase = qkv + (size_t)(b*SEQ)*QW + Dm + h*HDm;
  const bf16_t* vbase = vT + (size_t)bh*HDm*SEQ;
  const float scl = 0.08838834764831845f * 1.44269504089f; // 1/sqrt(128)*log2(e)

  auto stage = [&](int buf, int k0) {
    #pragma unroll
    for (int i = 0; i < 2; ++i) {
      const int s = tid + i*512;                 // K slot (1024 total)
      const int row = s >> 4, sl = s & 15;
      gload_lds16(kbase + (size_t)(k0 + row)*QW + (sl ^ (row & 7))*8, Ks[buf] + s*8);
    }
    #pragma unroll
    for (int i = 0; i < 2; ++i) {
      const int s = tid + i*512;                 // V slot (1024 total)
      const int row = s >> 3, sl = s & 7;
      gload_lds16(vbase + (size_t)row*SEQ + k0 + (sl ^ (row & 7))*8, Vs[buf] + s*8);
    }
  };

  bf16x8 qf[2][4];
  #pragma unroll
  for (int rt = 0; rt < 2; ++rt) {
    const bf16_t* qb = qkv + (size_t)(b*SEQ + q0w + rt*16 + lr)*QW + h*HDm;
    #pragma unroll
    for (int g = 0; g < 4; ++g)
      qf[rt][g] = *(const bf16x8*)(qb + g*32 + kg*8);
  }

  float mrow[2][4], lsum[2][4];
  f32x4 oacc[2][8];
  #pragma unroll
  for (int rt = 0; rt < 2; ++rt) {
    #pragma unroll
    for (int j = 0; j < 4; ++j) { mrow[rt][j] = -INFINITY; lsum[rt][j] = 0.f; }
    #pragma unroll
    for (int dt = 0; dt < 8; ++dt) oacc[rt][dt] = (f32x4){0.f,0.f,0.f,0.f};
  }

  const int NT = (16 - pr) * 2;                // union k-range of the pair
  stage(0, 0);
  asm volatile("s_waitcnt vmcnt(0)" ::: "memory");
  __syncthreads();
  for (int t = 0; t < NT; ++t) {
    const int k0 = t * 64;
    const int buf = t & 1;
    const bool more = (t + 1 < NT);
    if (more) stage(buf ^ 1, k0 + 64);
    if (k0 < q0w + 32) {
      f32x4 sa[2][4];
      #pragma unroll
      for (int rt = 0; rt < 2; ++rt)
        #pragma unroll
        for (int ct = 0; ct < 4; ++ct) sa[rt][ct] = (f32x4){0.f,0.f,0.f,0.f};
      #pragma unroll
      for (int ct = 0; ct < 4; ++ct) {
        const int krow = ct*16 + lr;
        #pragma unroll
        for (int g = 0; g < 4; ++g) {
          bf16x8 kf = *(const bf16x8*)(Ks[buf] + krow*128 + ((4*g + kg) ^ (krow & 7))*8);
          sa[0][ct] = __builtin_amdgcn_mfma_f32_16x16x32_bf16(qf[0][g], kf, sa[0][ct], 0, 0, 0);
          sa[1][ct] = __builtin_amdgcn_mfma_f32_16x16x32_bf16(qf[1][g], kf, sa[1][ct], 0, 0, 0);
        }
      }
      #pragma unroll
      for (int rt = 0; rt < 2; ++rt)
        #pragma unroll
        for (int ct = 0; ct < 4; ++ct)
          #pragma unroll
          for (int j = 0; j < 4; ++j) sa[rt][ct][j] *= scl;
      if (k0 + 63 > q0w) {
        #pragma unroll
        for (int ct = 0; ct < 4; ++ct) {
          const int kidx = k0 + ct*16 + lr;
          #pragma unroll
          for (int rt = 0; rt < 2; ++rt)
            #pragma unroll
            for (int j = 0; j < 4; ++j) {
              const int qidx = q0w + rt*16 + kg*4 + j;
              if (kidx > qidx) sa[rt][ct][j] = -INFINITY;
            }
        }
      }
      #pragma unroll
      for (int rt = 0; rt < 2; ++rt) {
        #pragma unroll
        for (int j = 0; j < 4; ++j) {
          const int prow = kg*4 + j;
          float x0 = sa[rt][0][j], x1 = sa[rt][1][j], x2 = sa[rt][2][j], x3 = sa[rt][3][j];
          float v = fmaxf(fmaxf(x0, x1), fmaxf(x2, x3));
          v = fmaxf(v, __shfl_xor(v, 1));
          v = fmaxf(v, __shfl_xor(v, 2));
          v = fmaxf(v, __shfl_xor(v, 4));
          v = fmaxf(v, __shfl_xor(v, 8));
          const float mn = fmaxf(mrow[rt][j], v);
          const float alpha = exp2f(mrow[rt][j] - mn);
          mrow[rt][j] = mn;
          float p0 = exp2f(x0 - mn), p1 = exp2f(x1 - mn);
          float p2 = exp2f(x2 - mn), p3 = exp2f(x3 - mn);
          float ss = (p0 + p1) + (p2 + p3);
          ss += __shfl_xor(ss, 1);
          ss += __shfl_xor(ss, 2);
          ss += __shfl_xor(ss, 4);
          ss += __shfl_xor(ss, 8);
          lsum[rt][j] = lsum[rt][j]*alpha + ss;
          #pragma unroll
          for (int dt = 0; dt < 8; ++dt) oacc[rt][dt][j] *= alpha;
          const int base = w*2048 + rt*1024 + prow*64;
          const int sw = (prow & 7) << 3;
          Plds[(base + ( 0 + lr)) ^ sw] = (bf16_t)p0;
          Plds[(base + (16 + lr)) ^ sw] = (bf16_t)p1;
          Plds[(base + (32 + lr)) ^ sw] = (bf16_t)p2;
          Plds[(base + (48 + lr)) ^ sw] = (bf16_t)p3;
        }
      }
      bf16x8 pf[2][2];
      {
        const int sw = (lr & 7) << 3;
        #pragma unroll
        for (int rt = 0; rt < 2; ++rt) {
          pf[rt][0] = *(const bf16x8*)(Plds + ((w*2048 + rt*1024 + lr*64 +      kg*8) ^ sw));
          pf[rt][1] = *(const bf16x8*)(Plds + ((w*2048 + rt*1024 + lr*64 + 32 + kg*8) ^ sw));
        }
      }
      #pragma unroll
      for (int dt = 0; dt < 8; ++dt) {
        const int vrow = dt*16 + lr;
        #pragma unroll
        for (int kc = 0; kc < 2; ++kc) {
          bf16x8 vf = *(const bf16x8*)(Vs[buf] + vrow*64 + ((4*kc + kg) ^ (vrow & 7))*8);
          oacc[0][dt] = __builtin_amdgcn_mfma_f32_16x16x32_bf16(pf[0][kc], vf, oacc[0][dt], 0, 0, 0);
          oacc[1][dt] = __builtin_amdgcn_mfma_f32_16x16x32_bf16(pf[1][kc], vf, oacc[1][dt], 0, 0, 0);
        }
      }
    }
    if (more) asm volatile("s_waitcnt vmcnt(0)" ::: "memory");
    __syncthreads();
  }

  #pragma unroll
  for (int rt = 0; rt < 2; ++rt) {
    bf16_t* cb = ctx + (size_t)(b*SEQ + q0w + rt*16 + kg*4)*Dm + h*HDm;
    #pragma unroll
    for (int j = 0; j < 4; ++j) {
      const float inv = 1.f / lsum[rt][j];
      #pragma unroll
      for (int dt = 0; dt < 8; ++dt)
        cb[(size_t)j*Dm + dt*16 + lr] = (bf16_t)(oacc[rt][dt][j] * inv);
    }
  }
}

} // namespace

extern "C" void kernel_launch(void* const* d_in, const int* in_sizes, int n_in,
                              void* d_out, int out_size, void* d_ws, size_t ws_size,
                              hipStream_t stream)
{
  const float* x   = (const float*)d_in[0];
  const float* g1  = (const float*)d_in[1];
  const float* s1  = (const float*)d_in[2];
  const float* wq  = (const float*)d_in[3];
  const float* bq  = (const float*)d_in[4];
  const float* wk  = (const float*)d_in[5];
  const float* bk  = (const float*)d_in[6];
  const float* wv  = (const float*)d_in[7];
  const float* bv  = (const float*)d_in[8];
  const float* wo  = (const float*)d_in[9];
  const float* bo  = (const float*)d_in[10];
  const float* g2  = (const float*)d_in[11];
  const float* s2  = (const float*)d_in[12];
  const float* w1  = (const float*)d_in[13];
  const float* b1  = (const float*)d_in[14];
  const float* w2  = (const float*)d_in[15];
  const float* b2  = (const float*)d_in[16];
  float* out = (float*)d_out;

  char* p = (char*)d_ws;
  bf16_t* wqkvT = (bf16_t*)p;  p += (size_t)QW*Dm*2;     // + woT right after
  bf16_t* woT   = (bf16_t*)p;  p += (size_t)Dm*Dm*2;
  bf16_t* w1T   = (bf16_t*)p;  p += (size_t)FFm*Dm*2;
  bf16_t* w2T   = (bf16_t*)p;  p += (size_t)Dm*FFm*2;
  float*  bqkv  = (float*)p;   p += (size_t)QW*4;
  bf16_t* hbuf  = (bf16_t*)p;  p += (size_t)MR*Dm*2;
  bf16_t* qkv   = (bf16_t*)p;  p += (size_t)MR*QW*2;
  bf16_t* vTb   = (bf16_t*)p;  p += (size_t)32*HDm*SEQ*2;
  bf16_t* ctx   = (bf16_t*)p;  p += (size_t)MR*Dm*2;
  float*  x1    = (float*)p;   p += (size_t)MR*Dm*4;
  bf16_t* ffn1  = qkv;                  // FFN1 out: spans qkv+vTb (67.1 MB)
  float*  prj0  = (float*)qkv;
  float*  prj1  = (float*)qkv + (size_t)MR*Dm;
  float*  f2p0  = (float*)w1T;
  float*  f2p1  = (float*)wqkvT;
  // V-partials (bf16) live in x1's region (dead until ln_fused)
  bf16_t* vp0   = (bf16_t*)x1;
  bf16_t* vp1   = (bf16_t*)x1 + (size_t)MR*Dm;

  wconv4<<<dim3(Dm/32, Dm/32, 4), 256, 0, stream>>>(wq, wk, wv, wo, wqkvT);
  wconv_t<<<dim3(FFm/32, Dm/32), 256, 0, stream>>>(w1, w1T, Dm, FFm);
  wconv_t<<<dim3(Dm/32, FFm/32), 256, 0, stream>>>(w2, w2T, FFm, Dm);
  bias_concat<<<dim3(Dm/256), 256, 0, stream>>>(bq, bk, bv, bqkv);

  ln_kernel<<<dim3(MR), 256, 0, stream>>>(x, g1, s1, hbuf);
  // QK: N=4096 (256 tiles = 1 full round), writes qkv cols 0..4095 (stride QW)
  gemm8p<0><<<dim3((4096/256)*(MR/256), 1), 512, 0, stream>>>(
      hbuf, wqkvT, bqkv, qkv, nullptr, QW, Dm, Dm, 4096/256);
  // V: split-K=2 (128x2 = 256 blocks = 1 round), bf16 raw partials
  gemm8p<4><<<dim3((Dm/256)*(MR/256), 2), 512, 0, stream>>>(
      hbuf, wqkvT + (size_t)2*Dm*Dm, nullptr, vp0, vp1, Dm, Dm/2, Dm, Dm/256);
  vtrans_fused<<<dim3(SEQ/32, HDm/32, 32), 256, 0, stream>>>(vp0, vp1, bv, vTb);
  flash_attn7<<<dim3(256), 512, 0, stream>>>(qkv, vTb, ctx);
  gemm8p<3><<<dim3((Dm/256)*(MR/256), 2), 512, 0, stream>>>(
      ctx, woT, nullptr, prj0, prj1, Dm, Dm/2, Dm, Dm/256);
  // fused: x1 = prj0+prj1+bo+x ; hbuf = LN2(x1)
  ln_fused<<<dim3(MR), 256, 0, stream>>>(prj0, prj1, bo, x, g2, s2, x1, hbuf);
  gemm8p<1><<<dim3((FFm/256)*(MR/256), 1), 512, 0, stream>>>(
      hbuf, w1T, b1, ffn1, nullptr, FFm, Dm, Dm, FFm/256);
  gemm8p<3><<<dim3((Dm/256)*(MR/256), 2), 512, 0, stream>>>(
      ffn1, w2T, nullptr, f2p0, f2p1, Dm, FFm/2, FFm, Dm/256);
  splitk_reduce<<<dim3(MR*Dm/1024), 256, 0, stream>>>(f2p0, f2p1, b2, x1, out, Dm);
}

// Round 20
// 636.348 us; speedup vs baseline: 1.1110x; 1.0164x over previous
//
#include <hip/hip_runtime.h>
#include <hip/hip_bf16.h>
#include <math.h>

namespace {

constexpr int Dm  = 2048;
constexpr int FFm = 8192;
constexpr int SEQ = 2048;
constexpr int HDm = 128;
constexpr int MR  = 4096;     // B*S
constexpr int QW  = 3 * Dm;   // 6144

typedef __bf16 bf16_t;
typedef __bf16 bf16x8 __attribute__((ext_vector_type(8)));
typedef float  f32x4  __attribute__((ext_vector_type(4)));

typedef __attribute__((address_space(1))) const void as1_void;
typedef __attribute__((address_space(3))) void as3_void;

__device__ __forceinline__ void gload_lds16(const void* g, void* l) {
  __builtin_amdgcn_global_load_lds((as1_void*)g, (as3_void*)l, 16, 0, 0);
}

// ---------------- LayerNorm: fp32 in -> bf16 out ----------------
__global__ __launch_bounds__(256)
void ln_kernel(const float* __restrict__ x, const float* __restrict__ sc,
               const float* __restrict__ sh, bf16_t* __restrict__ out)
{
  const int row = blockIdx.x;
  const int tid = threadIdx.x;
  const float4* xr = (const float4*)(x + (size_t)row * Dm);
  float4 v0 = xr[tid*2], v1 = xr[tid*2+1];
  float s  = v0.x+v0.y+v0.z+v0.w + v1.x+v1.y+v1.z+v1.w;
  float s2 = v0.x*v0.x+v0.y*v0.y+v0.z*v0.z+v0.w*v0.w
           + v1.x*v1.x+v1.y*v1.y+v1.z*v1.z+v1.w*v1.w;
  #pragma unroll
  for (int off = 32; off; off >>= 1) { s += __shfl_xor(s, off); s2 += __shfl_xor(s2, off); }
  __shared__ float red[8];
  if ((tid & 63) == 0) { red[(tid>>6)*2] = s; red[(tid>>6)*2+1] = s2; }
  __syncthreads();
  s  = red[0]+red[2]+red[4]+red[6];
  s2 = red[1]+red[3]+red[5]+red[7];
  const float mean = s * (1.f/Dm);
  const float var  = fmaxf(s2 * (1.f/Dm) - mean*mean, 0.f);
  const float rstd = rsqrtf(var + 1e-5f);
  const float4* scp = (const float4*)sc;
  const float4* shp = (const float4*)sh;
  float4 sc0 = scp[tid*2], sc1 = scp[tid*2+1];
  float4 sh0 = shp[tid*2], sh1 = shp[tid*2+1];
  __attribute__((aligned(16))) bf16_t ob[8];
  ob[0] = (bf16_t)((v0.x-mean)*rstd*sc0.x + sh0.x);
  ob[1] = (bf16_t)((v0.y-mean)*rstd*sc0.y + sh0.y);
  ob[2] = (bf16_t)((v0.z-mean)*rstd*sc0.z + sh0.z);
  ob[3] = (bf16_t)((v0.w-mean)*rstd*sc0.w + sh0.w);
  ob[4] = (bf16_t)((v1.x-mean)*rstd*sc1.x + sh1.x);
  ob[5] = (bf16_t)((v1.y-mean)*rstd*sc1.y + sh1.y);
  ob[6] = (bf16_t)((v1.z-mean)*rstd*sc1.z + sh1.z);
  ob[7] = (bf16_t)((v1.w-mean)*rstd*sc1.w + sh1.w);
  *(uint4*)(out + (size_t)row*Dm + tid*8) = *(const uint4*)ob;
}

// -- fused (bf16 partials): v = p0+p1+bias+resid; x1 = v; out = LN(v) --
__global__ __launch_bounds__(256)
void ln_fused_bf(const bf16_t* __restrict__ p0, const bf16_t* __restrict__ p1,
                 const float* __restrict__ bias, const float* __restrict__ resid,
                 const float* __restrict__ sc, const float* __restrict__ sh,
                 float* __restrict__ x1, bf16_t* __restrict__ out)
{
  const int row = blockIdx.x;
  const int tid = threadIdx.x;
  const size_t base = (size_t)row * Dm + tid*8;
  bf16x8 a = *(const bf16x8*)(p0 + base);
  bf16x8 b = *(const bf16x8*)(p1 + base);
  float v[8];
  #pragma unroll
  for (int hh = 0; hh < 2; ++hh) {
    float4 r  = *(const float4*)(resid + base + hh*4);
    float4 bv = *(const float4*)(bias + tid*8 + hh*4);
    v[hh*4+0] = (float)a[hh*4+0] + (float)b[hh*4+0] + bv.x + r.x;
    v[hh*4+1] = (float)a[hh*4+1] + (float)b[hh*4+1] + bv.y + r.y;
    v[hh*4+2] = (float)a[hh*4+2] + (float)b[hh*4+2] + bv.z + r.z;
    v[hh*4+3] = (float)a[hh*4+3] + (float)b[hh*4+3] + bv.w + r.w;
  }
  *(float4*)(x1 + base)     = *(const float4*)&v[0];
  *(float4*)(x1 + base + 4) = *(const float4*)&v[4];
  float s = 0.f, s2 = 0.f;
  #pragma unroll
  for (int j = 0; j < 8; ++j) { s += v[j]; s2 += v[j]*v[j]; }
  #pragma unroll
  for (int off = 32; off; off >>= 1) { s += __shfl_xor(s, off); s2 += __shfl_xor(s2, off); }
  __shared__ float red[8];
  if ((tid & 63) == 0) { red[(tid>>6)*2] = s; red[(tid>>6)*2+1] = s2; }
  __syncthreads();
  s  = red[0]+red[2]+red[4]+red[6];
  s2 = red[1]+red[3]+red[5]+red[7];
  const float mean = s * (1.f/Dm);
  const float var  = fmaxf(s2 * (1.f/Dm) - mean*mean, 0.f);
  const float rstd = rsqrtf(var + 1e-5f);
  __attribute__((aligned(16))) bf16_t ob[8];
  #pragma unroll
  for (int hh = 0; hh < 2; ++hh) {
    float4 scv = *(const float4*)(sc + tid*8 + hh*4);
    float4 shv = *(const float4*)(sh + tid*8 + hh*4);
    ob[hh*4+0] = (bf16_t)((v[hh*4+0]-mean)*rstd*scv.x + shv.x);
    ob[hh*4+1] = (bf16_t)((v[hh*4+1]-mean)*rstd*scv.y + shv.y);
    ob[hh*4+2] = (bf16_t)((v[hh*4+2]-mean)*rstd*scv.z + shv.z);
    ob[hh*4+3] = (bf16_t)((v[hh*4+3]-mean)*rstd*scv.w + shv.w);
  }
  *(uint4*)(out + base) = *(const uint4*)ob;
}

// ----- weights q,k,v,o (each [Dm][Dm] fp32) -> bf16 transposed, packed -----
__global__ __launch_bounds__(256)
void wconv4(const float* __restrict__ wq, const float* __restrict__ wk,
            const float* __restrict__ wv, const float* __restrict__ wo,
            bf16_t* __restrict__ dst)
{
  const int z = blockIdx.z;
  const float* W = (z == 0) ? wq : (z == 1) ? wk : (z == 2) ? wv : wo;
  bf16_t* WT = dst + (size_t)z * Dm * Dm;
  __shared__ float tile[32][33];
  const int tx = threadIdx.x & 31, ty = threadIdx.x >> 5;
  const int nb = blockIdx.x * 32, kb = blockIdx.y * 32;
  #pragma unroll
  for (int p = 0; p < 4; ++p)
    tile[ty+8*p][tx] = W[(size_t)(kb+ty+8*p)*Dm + nb + tx];
  __syncthreads();
  #pragma unroll
  for (int p = 0; p < 4; ++p)
    WT[(size_t)(nb+ty+8*p)*Dm + kb + tx] = (bf16_t)tile[tx][ty+8*p];
}

// ------------- weight fp32 [K][N] -> bf16 transposed [N][K] -------------
__global__ __launch_bounds__(256)
void wconv_t(const float* __restrict__ W, bf16_t* __restrict__ WT, int K, int N)
{
  __shared__ float tile[32][33];
  const int tx = threadIdx.x & 31, ty = threadIdx.x >> 5;
  const int nb = blockIdx.x * 32, kb = blockIdx.y * 32;
  #pragma unroll
  for (int p = 0; p < 4; ++p)
    tile[ty+8*p][tx] = W[(size_t)(kb+ty+8*p)*N + nb + tx];
  __syncthreads();
  #pragma unroll
  for (int p = 0; p < 4; ++p)
    WT[(size_t)(nb+ty+8*p)*K + kb + tx] = (bf16_t)tile[tx][ty+8*p];
}

__global__ void bias_concat(const float* __restrict__ bq, const float* __restrict__ bk,
                            const float* __restrict__ bv, float* __restrict__ o)
{
  int i = blockIdx.x*256 + threadIdx.x;
  o[i] = bq[i]; o[Dm+i] = bk[i]; o[2*Dm+i] = bv[i];
}

// ----- V partials [B*S][2048] (bf16 x2) + bias -> vT [B*H][128][2048] -----
__global__ __launch_bounds__(256)
void vtrans_fused(const bf16_t* __restrict__ vp0, const bf16_t* __restrict__ vp1,
                  const float* __restrict__ bv, bf16_t* __restrict__ vT)
{
  __shared__ bf16_t tile[32][33];
  const int tx = threadIdx.x & 31, ty = threadIdx.x >> 5;
  const int s0 = blockIdx.x*32, d0 = blockIdx.y*32, bh = blockIdx.z;
  const int b = bh >> 4, h = bh & 15;
  const int gd = h*HDm + d0 + tx;                 // global V column
  const float bias = bv[gd];
  #pragma unroll
  for (int p = 0; p < 4; ++p) {
    const size_t idx = (size_t)(b*SEQ + s0 + ty + 8*p)*Dm + gd;
    tile[ty+8*p][tx] = (bf16_t)((float)vp0[idx] + (float)vp1[idx] + bias);
  }
  __syncthreads();
  bf16_t* dst = vT + (size_t)bh*HDm*SEQ;
  #pragma unroll
  for (int p = 0; p < 4; ++p)
    dst[(size_t)(d0+ty+8*p)*SEQ + s0 + tx] = tile[tx][ty+8*p];
}

// ---- GEMM 256x256, 8-phase, 2 K-tiles(BK=64)/iter, 8 waves (2Mx4N) ----
// MODE: 0 bf16+bias | 1 bf16+bias+GELU | 3 f32 raw partial | 4 bf16 raw partial
template<int MODE>
__global__ __launch_bounds__(512, 2)
void gemm8p(const bf16_t* __restrict__ A, const bf16_t* __restrict__ BT,
            const float* __restrict__ bias,
            void* __restrict__ Cout, void* __restrict__ Cout2,
            int Ndim, int Kslice, int Kstride, int gn)
{
  // 2D XCD chunking: 2x4 chunk grid; chunk = bid&7 (XCD-pinned)
  const int gm = (int)gridDim.x / gn;
  const int cm = gm >> 1, cn = gn >> 2;
  const int c = blockIdx.x & 7;
  const int idx = blockIdx.x >> 3;
  const int mi = idx / cn, ni = idx - mi*cn;
  const int m0 = ((c >> 2)*cm + mi) * 256;
  const int n0 = ((c & 3)*cn + ni) * 256;
  const int kOff = blockIdx.y * Kslice;
  const int tid = threadIdx.x;
  const int lane = tid & 63;
  const int w = tid >> 6;
  const int wr = w >> 2, wc = w & 3;              // 2 x 4 waves
  const int lr = lane & 15, kg = lane >> 4;

  // 8 regions of 8192 elems: buf0{r0:A-h0, r1:A-h1, r2:B-h0, r3:B-h1} buf1{r4..r7}
  __shared__ __attribute__((aligned(16))) bf16_t lds[65536];

  f32x4 acc[8][4] = {};

  // --- staging: 4 streams, incremental pointers (+64 elems per call) ---
  const int r1   = tid >> 3;
  const int blk1 = (tid & 7) ^ (r1 & 7);
  const size_t rowoff = (size_t)64 * Kstride;
  const bf16_t* pA0 = A  + (size_t)(m0 + r1)*Kstride       + kOff + blk1*8;
  const bf16_t* pA1 = A  + (size_t)(m0 + 128 + r1)*Kstride + kOff + blk1*8;
  const bf16_t* pB0 = BT + (size_t)(n0 + r1)*Kstride       + kOff + blk1*8;
  const bf16_t* pB1 = BT + (size_t)(n0 + 128 + r1)*Kstride + kOff + blk1*8;
  bf16_t* const d0 = lds + (size_t)tid*8;

#define STG(p, region) do { \
    gload_lds16((p), d0 + (size_t)(region)*8192); \
    gload_lds16((p) + rowoff, d0 + (size_t)(region)*8192 + 4096); \
    (p) += 64; } while (0)

  // read A-half mh: rows wr*64 + ml*16 + lr within region (buf*4 + mh)
  auto readA = [&](int buf, int mh, bf16x8* f) {
    #pragma unroll
    for (int ml = 0; ml < 4; ++ml)
      #pragma unroll
      for (int kk = 0; kk < 2; ++kk) {
        const bf16_t* base = lds + (buf*4 + mh)*8192;
        const int row = wr*64 + ml*16 + lr;
        f[ml*2+kk] = *(const bf16x8*)(base + row*64 + (((kk*4+kg) ^ (row&7))*8));
      }
  };
  // read B-half nh: rows wc*32 + nl*16 + lr within region (buf*4 + 2 + nh)
  auto readB = [&](int buf, int nh, bf16x8* f) {
    #pragma unroll
    for (int nl = 0; nl < 2; ++nl)
      #pragma unroll
      for (int kk = 0; kk < 2; ++kk) {
        const bf16_t* base = lds + (buf*4 + 2 + nh)*8192;
        const int row = wc*32 + nl*16 + lr;
        f[nl*2+kk] = *(const bf16x8*)(base + row*64 + (((kk*4+kg) ^ (row&7))*8));
      }
  };
  auto mfma16 = [&](int mh, int nh, const bf16x8* Af, const bf16x8* Bf) {
    __builtin_amdgcn_s_setprio(1);
    #pragma unroll
    for (int ml = 0; ml < 4; ++ml)
      #pragma unroll
      for (int nl = 0; nl < 2; ++nl)
        #pragma unroll
        for (int kk = 0; kk < 2; ++kk)
          acc[mh*4+ml][nh*2+nl] =
            __builtin_amdgcn_mfma_f32_16x16x32_bf16(Af[ml*2+kk], Bf[nl*2+kk],
                                                    acc[mh*4+ml][nh*2+nl], 0, 0, 0);
    __builtin_amdgcn_s_setprio(0);
  };

#define BAR() __builtin_amdgcn_s_barrier()
#define LGKM0() asm volatile("s_waitcnt lgkmcnt(0)")

  bf16x8 Af0[8], Af1[8], Bf0[4], Bf1[4];      // even K-tile set
  bf16x8 Af0b[8], Af1b[8], Bf0b[4], Bf1b[4];  // odd K-tile set

  // prologue: stage t0 (r0-r3) then t1 (r4-r7); vmcnt(8) -> t0 resident.
  STG(pA0, 0); STG(pA1, 1); STG(pB0, 2); STG(pB1, 3);
  STG(pA0, 4); STG(pA1, 5); STG(pB0, 6); STG(pB1, 7);
  asm volatile("s_waitcnt vmcnt(8)" ::: "memory");
  BAR();

  const int NITER = Kslice >> 7;     // iterations of 2 K-tiles
  for (int j = 0; j < NITER; ++j) {
    const bool s2 = (j + 1 < NITER);

    // P1: reads r0 (A-h0 t0) + r2 (B-h0 t0); no stage
    readA(0, 0, Af0); readB(0, 0, Bf0);
    BAR(); LGKM0(); mfma16(0, 0, Af0, Bf0); BAR();

    // P2: reads r3 (B-h1 t0); stage r0 <- A-h0(t0+2)   [r0 last read P1]
    readB(0, 1, Bf1);
    if (s2) STG(pA0, 0);
    BAR(); LGKM0(); mfma16(0, 1, Af0, Bf1); BAR();

    // P3: reads r1 (A-h1 t0); stage r2 <- B-h0(t0+2)   [r2 last read P1]
    readA(0, 1, Af1);
    if (s2) STG(pB0, 2);
    BAR(); LGKM0(); mfma16(1, 1, Af1, Bf1);
    if (s2) asm volatile("s_waitcnt vmcnt(4)" ::: "memory");
    else    asm volatile("s_waitcnt vmcnt(0)" ::: "memory");
    BAR();

    // P4: reads r4 (A-h0 t1); stage r1 <- A-h1(t0+2), r3 <- B-h1(t0+2)
    readA(1, 0, Af0b);
    if (s2) { STG(pA1, 1); STG(pB1, 3); }
    BAR(); LGKM0(); mfma16(1, 0, Af1, Bf0); BAR();

    // P5: reads r6 (B-h0 t1); no stage
    readB(1, 0, Bf0b);
    BAR(); LGKM0(); mfma16(0, 0, Af0b, Bf0b); BAR();

    // P6: reads r7 (B-h1 t1); stage r4 <- A-h0(t1+2), r6 <- B-h0(t1+2)
    readB(1, 1, Bf1b);
    if (s2) { STG(pA0, 4); STG(pB0, 6); }
    BAR(); LGKM0(); mfma16(0, 1, Af0b, Bf1b); BAR();

    // P7: reads r5 (A-h1 t1); stage r7 <- B-h1(t1+2)   [r7 last read P6]
    readA(1, 1, Af1b);
    if (s2) STG(pB1, 7);
    BAR(); LGKM0(); mfma16(1, 1, Af1b, Bf1b); BAR();

    // P8: stage r5 <- A-h1(t1+2)                       [r5 last read P7]
    if (s2) STG(pA1, 5);
    BAR(); mfma16(1, 0, Af1b, Bf0b);
    if (s2) asm volatile("s_waitcnt vmcnt(8)" ::: "memory");
    else    asm volatile("s_waitcnt vmcnt(0)" ::: "memory");
    BAR();
  }
#undef STG
#undef BAR
#undef LGKM0

  // ---- epilogue ----
  // row(MF) = (MF>>2)*128 + wr*64 + (MF&3)*16 + kg*4 + jj
  // col(NF) = (NF>>1)*128 + wc*32 + (NF&1)*16 + lr
  if constexpr (MODE == 0 || MODE == 1 || MODE == 4) {
    __syncthreads();
    #pragma unroll
    for (int NF = 0; NF < 4; ++NF) {
      const int col = (NF>>1)*128 + wc*32 + (NF&1)*16 + lr;
      float bv = 0.f;
      if constexpr (MODE != 4) bv = bias[n0 + col];
      #pragma unroll
      for (int MF = 0; MF < 8; ++MF) {
        #pragma unroll
        for (int jj = 0; jj < 4; ++jj) {
          float v = acc[MF][NF][jj] + bv;
          if constexpr (MODE == 1) v = 0.5f*v*(1.f + erff(v*0.70710678118f));
          const int row = (MF>>2)*128 + wr*64 + (MF&3)*16 + kg*4 + jj;
          const int adr = row*256 + (((col >> 3) ^ (row & 7)) << 3) + (col & 7);
          lds[adr] = (bf16_t)v;
        }
      }
    }
    __syncthreads();
    bf16_t* outp;
    if constexpr (MODE == 4) outp = (bf16_t*)(blockIdx.y ? Cout2 : Cout);
    else                     outp = (bf16_t*)Cout;
    #pragma unroll
    for (int i = 0; i < 16; ++i) {
      const int s = tid + i*512;
      const int row = s >> 5, ch = s & 31;
      uint4 vv = *(const uint4*)(lds + row*256 + ((ch ^ (row & 7)) << 3));
      *(uint4*)(outp + (size_t)(m0 + row)*Ndim + n0 + ch*8) = vv;
    }
  } else {
    float* pout = (float*)(blockIdx.y ? Cout2 : Cout);
    #pragma unroll
    for (int NF = 0; NF < 4; ++NF) {
      const int col = n0 + (NF>>1)*128 + wc*32 + (NF&1)*16 + lr;
      #pragma unroll
      for (int MF = 0; MF < 8; ++MF) {
        const int rbase = m0 + (MF>>2)*128 + wr*64 + (MF&3)*16 + kg*4;
        #pragma unroll
        for (int jj = 0; jj < 4; ++jj)
          pout[(size_t)(rbase + jj)*Ndim + col] = acc[MF][NF][jj];
      }
    }
  }
}

// -- split-K reduce (bf16 partials): out = p0+p1+bias+resid (f32 out) --
__global__ __launch_bounds__(256)
void splitk_reduce_bf(const bf16_t* __restrict__ p0, const bf16_t* __restrict__ p1,
                      const float* __restrict__ bias, const float* __restrict__ resid,
                      float* __restrict__ out, int Ndim)
{
  const size_t e = ((size_t)blockIdx.x*256 + threadIdx.x) * 8;
  bf16x8 a = *(const bf16x8*)(p0 + e);
  bf16x8 b = *(const bf16x8*)(p1 + e);
  const int col = (int)(e & (size_t)(Ndim - 1));
  #pragma unroll
  for (int hh = 0; hh < 2; ++hh) {
    float4 r  = *(const float4*)(resid + e + hh*4);
    float4 bv = *(const float4*)(bias + col + hh*4);
    float4 o;
    o.x = (float)a[hh*4+0] + (float)b[hh*4+0] + bv.x + r.x;
    o.y = (float)a[hh*4+1] + (float)b[hh*4+1] + bv.y + r.y;
    o.z = (float)a[hh*4+2] + (float)b[hh*4+2] + bv.z + r.z;
    o.w = (float)a[hh*4+3] + (float)b[hh*4+3] + bv.w + r.w;
    *(float4*)(out + e + hh*4) = o;
  }
}

// ---- causal flash attention v7: fused balanced pair + K/V double-buffer ----
__global__ __launch_bounds__(512)
void flash_attn7(const bf16_t* __restrict__ qkv, const bf16_t* __restrict__ vT,
                 bf16_t* __restrict__ ctx)
{
  const int bid = blockIdx.x;                  // 0..255
  const int bh  = (bid & 7) + 8 * ((bid >> 3) & 3);  // XCD-pinned head
  const int pr  = bid >> 5;                    // 0..7 pair index
  const int b = bh >> 4, h = bh & 15;
  const int tid = threadIdx.x;
  const int lane = tid & 63;
  const int w = tid >> 6;                      // 0..7
  const int wg = w >> 2;                       // 0: qi=pr, 1: qi=15-pr
  const int wsub = w & 3;
  const int lr = lane & 15, kg = lane >> 4;

  const int qi = wg ? (15 - pr) : pr;
  const int Q0 = qi * 128;
  const int q0w = Q0 + wsub * 32;

  __shared__ __attribute__((aligned(16))) bf16_t Ks[2][64*128];
  __shared__ __attribute__((aligned(16))) bf16_t Vs[2][128*64];
  __shared__ __attribute__((aligned(16))) bf16_t Plds[8*2048];

  const bf16_t* kbase = qkv + (size_t)(b*SEQ)*QW + Dm + h*HDm;
  const bf16_t* vbase = vT + (size_t)bh*HDm*SEQ;
  const float scl = 0.08838834764831845f * 1.44269504089f; // 1/sqrt(128)*log2(e)

  auto stage = [&](int buf, int k0) {
    #pragma unroll
    for (int i = 0; i < 2; ++i) {
      const int s = tid + i*512;                 // K slot (1024 total)
      const int row = s >> 4, sl = s & 15;
      gload_lds16(kbase + (size_t)(k0 + row)*QW + (sl ^ (row & 7))*8, Ks[buf] + s*8);
    }
    #pragma unroll
    for (int i = 0; i < 2; ++i) {
      const int s = tid + i*512;                 // V slot (1024 total)
      const int row = s >> 3, sl = s & 7;
      gload_lds16(vbase + (size_t)row*SEQ + k0 + (sl ^ (row & 7))*8, Vs[buf] + s*8);
    }
  };

  bf16x8 qf[2][4];
  #pragma unroll
  for (int rt = 0; rt < 2; ++rt) {
    const bf16_t* qb = qkv + (size_t)(b*SEQ + q0w + rt*16 + lr)*QW + h*HDm;
    #pragma unroll
    for (int g = 0; g < 4; ++g)
      qf[rt][g] = *(const bf16x8*)(qb + g*32 + kg*8);
  }

  float mrow[2][4], lsum[2][4];
  f32x4 oacc[2][8];
  #pragma unroll
  for (int rt = 0; rt < 2; ++rt) {
    #pragma unroll
    for (int j = 0; j < 4; ++j) { mrow[rt][j] = -INFINITY; lsum[rt][j] = 0.f; }
    #pragma unroll
    for (int dt = 0; dt < 8; ++dt) oacc[rt][dt] = (f32x4){0.f,0.f,0.f,0.f};
  }

  const int NT = (16 - pr) * 2;                // union k-range of the pair
  stage(0, 0);
  asm volatile("s_waitcnt vmcnt(0)" ::: "memory");
  __syncthreads();
  for (int t = 0; t < NT; ++t) {
    const int k0 = t * 64;
    const int buf = t & 1;
    const bool more = (t + 1 < NT);
    if (more) stage(buf ^ 1, k0 + 64);
    if (k0 < q0w + 32) {
      f32x4 sa[2][4];
      #pragma unroll
      for (int rt = 0; rt < 2; ++rt)
        #pragma unroll
        for (int ct = 0; ct < 4; ++ct) sa[rt][ct] = (f32x4){0.f,0.f,0.f,0.f};
      #pragma unroll
      for (int ct = 0; ct < 4; ++ct) {
        const int krow = ct*16 + lr;
        #pragma unroll
        for (int g = 0; g < 4; ++g) {
          bf16x8 kf = *(const bf16x8*)(Ks[buf] + krow*128 + ((4*g + kg) ^ (krow & 7))*8);
          sa[0][ct] = __builtin_amdgcn_mfma_f32_16x16x32_bf16(qf[0][g], kf, sa[0][ct], 0, 0, 0);
          sa[1][ct] = __builtin_amdgcn_mfma_f32_16x16x32_bf16(qf[1][g], kf, sa[1][ct], 0, 0, 0);
        }
      }
      #pragma unroll
      for (int rt = 0; rt < 2; ++rt)
        #pragma unroll
        for (int ct = 0; ct < 4; ++ct)
          #pragma unroll
          for (int j = 0; j < 4; ++j) sa[rt][ct][j] *= scl;
      if (k0 + 63 > q0w) {
        #pragma unroll
        for (int ct = 0; ct < 4; ++ct) {
          const int kidx = k0 + ct*16 + lr;
          #pragma unroll
          for (int rt = 0; rt < 2; ++rt)
            #pragma unroll
            for (int j = 0; j < 4; ++j) {
              const int qidx = q0w + rt*16 + kg*4 + j;
              if (kidx > qidx) sa[rt][ct][j] = -INFINITY;
            }
        }
      }
      #pragma unroll
      for (int rt = 0; rt < 2; ++rt) {
        #pragma unroll
        for (int j = 0; j < 4; ++j) {
          const int prow = kg*4 + j;
          float x0 = sa[rt][0][j], x1 = sa[rt][1][j], x2 = sa[rt][2][j], x3 = sa[rt][3][j];
          float v = fmaxf(fmaxf(x0, x1), fmaxf(x2, x3));
          v = fmaxf(v, __shfl_xor(v, 1));
          v = fmaxf(v, __shfl_xor(v, 2));
          v = fmaxf(v, __shfl_xor(v, 4));
          v = fmaxf(v, __shfl_xor(v, 8));
          const float mn = fmaxf(mrow[rt][j], v);
          const float alpha = exp2f(mrow[rt][j] - mn);
          mrow[rt][j] = mn;
          float p0 = exp2f(x0 - mn), p1 = exp2f(x1 - mn);
          float p2 = exp2f(x2 - mn), p3 = exp2f(x3 - mn);
          float ss = (p0 + p1) + (p2 + p3);
          ss += __shfl_xor(ss, 1);
          ss += __shfl_xor(ss, 2);
          ss += __shfl_xor(ss, 4);
          ss += __shfl_xor(ss, 8);
          lsum[rt][j] = lsum[rt][j]*alpha + ss;
          #pragma unroll
          for (int dt = 0; dt < 8; ++dt) oacc[rt][dt][j] *= alpha;
          const int base = w*2048 + rt*1024 + prow*64;
          const int sw = (prow & 7) << 3;
          Plds[(base + ( 0 + lr)) ^ sw] = (bf16_t)p0;
          Plds[(base + (16 + lr)) ^ sw] = (bf16_t)p1;
          Plds[(base + (32 + lr)) ^ sw] = (bf16_t)p2;
          Plds[(base + (48 + lr)) ^ sw] = (bf16_t)p3;
        }
      }
      bf16x8 pf[2][2];
      {
        const int sw = (lr & 7) << 3;
        #pragma unroll
        for (int rt = 0; rt < 2; ++rt) {
          pf[rt][0] = *(const bf16x8*)(Plds + ((w*2048 + rt*1024 + lr*64 +      kg*8) ^ sw));
          pf[rt][1] = *(const bf16x8*)(Plds + ((w*2048 + rt*1024 + lr*64 + 32 + kg*8) ^ sw));
        }
      }
      #pragma unroll
      for (int dt = 0; dt < 8; ++dt) {
        const int vrow = dt*16 + lr;
        #pragma unroll
        for (int kc = 0; kc < 2; ++kc) {
          bf16x8 vf = *(const bf16x8*)(Vs[buf] + vrow*64 + ((4*kc + kg) ^ (vrow & 7))*8);
          oacc[0][dt] = __builtin_amdgcn_mfma_f32_16x16x32_bf16(pf[0][kc], vf, oacc[0][dt], 0, 0, 0);
          oacc[1][dt] = __builtin_amdgcn_mfma_f32_16x16x32_bf16(pf[1][kc], vf, oacc[1][dt], 0, 0, 0);
        }
      }
    }
    if (more) asm volatile("s_waitcnt vmcnt(0)" ::: "memory");
    __syncthreads();
  }

  #pragma unroll
  for (int rt = 0; rt < 2; ++rt) {
    bf16_t* cb = ctx + (size_t)(b*SEQ + q0w + rt*16 + kg*4)*Dm + h*HDm;
    #pragma unroll
    for (int j = 0; j < 4; ++j) {
      const float inv = 1.f / lsum[rt][j];
      #pragma unroll
      for (int dt = 0; dt < 8; ++dt)
        cb[(size_t)j*Dm + dt*16 + lr] = (bf16_t)(oacc[rt][dt][j] * inv);
    }
  }
}

} // namespace

extern "C" void kernel_launch(void* const* d_in, const int* in_sizes, int n_in,
                              void* d_out, int out_size, void* d_ws, size_t ws_size,
                              hipStream_t stream)
{
  const float* x   = (const float*)d_in[0];
  const float* g1  = (const float*)d_in[1];
  const float* s1  = (const float*)d_in[2];
  const float* wq  = (const float*)d_in[3];
  const float* bq  = (const float*)d_in[4];
  const float* wk  = (const float*)d_in[5];
  const float* bk  = (const float*)d_in[6];
  const float* wv  = (const float*)d_in[7];
  const float* bv  = (const float*)d_in[8];
  const float* wo  = (const float*)d_in[9];
  const float* bo  = (const float*)d_in[10];
  const float* g2  = (const float*)d_in[11];
  const float* s2  = (const float*)d_in[12];
  const float* w1  = (const float*)d_in[13];
  const float* b1  = (const float*)d_in[14];
  const float* w2  = (const float*)d_in[15];
  const float* b2  = (const float*)d_in[16];
  float* out = (float*)d_out;

  char* p = (char*)d_ws;
  bf16_t* wqkvT = (bf16_t*)p;  p += (size_t)QW*Dm*2;     // + woT right after
  bf16_t* woT   = (bf16_t*)p;  p += (size_t)Dm*Dm*2;
  bf16_t* w1T   = (bf16_t*)p;  p += (size_t)FFm*Dm*2;
  bf16_t* w2T   = (bf16_t*)p;  p += (size_t)Dm*FFm*2;
  float*  bqkv  = (float*)p;   p += (size_t)QW*4;
  bf16_t* hbuf  = (bf16_t*)p;  p += (size_t)MR*Dm*2;
  bf16_t* qkv   = (bf16_t*)p;  p += (size_t)MR*QW*2;
  bf16_t* vTb   = (bf16_t*)p;  p += (size_t)32*HDm*SEQ*2;
  bf16_t* ctx   = (bf16_t*)p;  p += (size_t)MR*Dm*2;
  float*  x1    = (float*)p;   p += (size_t)MR*Dm*4;
  bf16_t* ffn1  = qkv;                  // FFN1 out: spans qkv+vTb (67.1 MB)
  // proj partials (bf16) in qkv region (dead after attention)
  bf16_t* prjb0 = (bf16_t*)qkv;
  bf16_t* prjb1 = (bf16_t*)qkv + (size_t)MR*Dm;
  // FFN2 partials (bf16) in w1T region (dead after FFN1): 2x16.78M elems fits
  bf16_t* f2b0  = (bf16_t*)w1T;
  bf16_t* f2b1  = (bf16_t*)w1T + (size_t)MR*Dm;
  // V-partials (bf16) live in x1's region (dead until ln_fused)
  bf16_t* vp0   = (bf16_t*)x1;
  bf16_t* vp1   = (bf16_t*)x1 + (size_t)MR*Dm;

  wconv4<<<dim3(Dm/32, Dm/32, 4), 256, 0, stream>>>(wq, wk, wv, wo, wqkvT);
  wconv_t<<<dim3(FFm/32, Dm/32), 256, 0, stream>>>(w1, w1T, Dm, FFm);
  wconv_t<<<dim3(Dm/32, FFm/32), 256, 0, stream>>>(w2, w2T, FFm, Dm);
  bias_concat<<<dim3(Dm/256), 256, 0, stream>>>(bq, bk, bv, bqkv);

  ln_kernel<<<dim3(MR), 256, 0, stream>>>(x, g1, s1, hbuf);
  // QK: N=4096 (256 tiles = 1 full round), writes qkv cols 0..4095 (stride QW)
  gemm8p<0><<<dim3((4096/256)*(MR/256), 1), 512, 0, stream>>>(
      hbuf, wqkvT, bqkv, qkv, nullptr, QW, Dm, Dm, 4096/256);
  // V: split-K=2 (128x2 = 256 blocks = 1 round), bf16 raw partials
  gemm8p<4><<<dim3((Dm/256)*(MR/256), 2), 512, 0, stream>>>(
      hbuf, wqkvT + (size_t)2*Dm*Dm, nullptr, vp0, vp1, Dm, Dm/2, Dm, Dm/256);
  vtrans_fused<<<dim3(SEQ/32, HDm/32, 32), 256, 0, stream>>>(vp0, vp1, bv, vTb);
  flash_attn7<<<dim3(256), 512, 0, stream>>>(qkv, vTb, ctx);
  // proj: split-K=2, bf16 partials -> ln_fused_bf
  gemm8p<4><<<dim3((Dm/256)*(MR/256), 2), 512, 0, stream>>>(
      ctx, woT, nullptr, prjb0, prjb1, Dm, Dm/2, Dm, Dm/256);
  ln_fused_bf<<<dim3(MR), 256, 0, stream>>>(prjb0, prjb1, bo, x, g2, s2, x1, hbuf);
  gemm8p<1><<<dim3((FFm/256)*(MR/256), 1), 512, 0, stream>>>(
      hbuf, w1T, b1, ffn1, nullptr, FFm, Dm, Dm, FFm/256);
  // FFN2: split-K=2, bf16 partials
  gemm8p<4><<<dim3((Dm/256)*(MR/256), 2), 512, 0, stream>>>(
      ffn1, w2T, nullptr, f2b0, f2b1, Dm, FFm/2, FFm, Dm/256);
  splitk_reduce_bf<<<dim3(MR*Dm/2048), 256, 0, stream>>>(f2b0, f2b1, b2, x1, out, Dm);
}